// Round 2
// baseline (2913.376 us; speedup 1.0000x reference)
//
#include <hip/hip_runtime.h>

#define NN 100000
#define FF 128
#define HH 64
#define CC 16
#define EE 1000000

__device__ __forceinline__ float fsig(float t)  { return 1.0f/(1.0f+__expf(-t)); }
__device__ __forceinline__ float ftanh(float t) { return 1.0f - 2.0f/(__expf(2.0f*t)+1.0f); }

// ---- Combined weights: W1 = W_ih @ W_con1 [192x128], b1 = b_ih + W_ih @ b_con1 (same for 2)
__global__ void precomp_kernel(const float* __restrict__ W_ih, const float* __restrict__ b_ih,
                               const float* __restrict__ Wc1,  const float* __restrict__ bc1,
                               const float* __restrict__ Wc2,  const float* __restrict__ bc2,
                               float* __restrict__ W1, float* __restrict__ b1,
                               float* __restrict__ W2, float* __restrict__ b2)
{
    int idx = blockIdx.x*blockDim.x + threadIdx.x;
    const int total = 192*128;
    if (idx < total) {
        int j = idx >> 7, k = idx & 127;
        float s1 = 0.f, s2 = 0.f;
        for (int m=0; m<64; ++m) {
            float wih = W_ih[j*64+m];
            s1 += wih * Wc1[m*128+k];
            s2 += wih * Wc2[m*128+k];
        }
        W1[idx] = s1; W2[idx] = s2;
    } else if (idx < total + 192) {
        int j = idx - total;
        float s1 = b_ih[j], s2 = b_ih[j];
        for (int m=0; m<64; ++m) {
            float wih = W_ih[j*64+m];
            s1 += wih * bc1[m];
            s2 += wih * bc2[m];
        }
        b1[j] = s1; b2[j] = s2;
    }
}

// ---- h = x @ W_first^T + b   (K=128 -> M=64). Thread j holds W row j in VGPRs.
__global__ __launch_bounds__(256) void lin_first_kernel(
    const float* __restrict__ X, const float* __restrict__ W,
    const float* __restrict__ b, float* __restrict__ Y)
{
    const int j   = threadIdx.x & 63;
    const int sub = threadIdx.x >> 6;   // 4 nodes per block-iteration
    float Wr[128];
    #pragma unroll
    for (int k=0;k<128;k+=4) {
        float4 v = *(const float4*)&W[j*128+k];
        Wr[k]=v.x; Wr[k+1]=v.y; Wr[k+2]=v.z; Wr[k+3]=v.w;
    }
    const float bj = b[j];
    for (int n0 = blockIdx.x*4; n0 < NN; n0 += gridDim.x*4) {
        int n = n0 + sub;
        float acc = bj;
        const float4* xr = (const float4*)&X[(long)n*FF];
        #pragma unroll
        for (int k4=0;k4<32;++k4) {
            float4 v = xr[k4];
            acc += v.x*Wr[4*k4] + v.y*Wr[4*k4+1] + v.z*Wr[4*k4+2] + v.w*Wr[4*k4+3];
        }
        Y[(long)n*HH + j] = acc;
    }
}

// ---- segment_sum scatter: out[dst] += X[src]*w. One wave per edge, lane = feature.
__global__ __launch_bounds__(256) void prop_kernel(
    const float* __restrict__ X, const int* __restrict__ ei,
    const float* __restrict__ w, float* __restrict__ out)
{
    int e    = blockIdx.x*4 + (threadIdx.x>>6);
    int lane = threadIdx.x & 63;
    if (e >= EE) return;
    int   src = ei[e];
    int   dst = ei[EE + e];
    float wt  = w[e];
    float v = X[(long)src*HH + lane] * wt;
    atomicAdd(&out[(long)dst*HH + lane], v);
}

// ---- fused layer v2 (split-K): 384 threads = (j in 0..191) x (half in 0..1).
// Thread (j,half) holds Wg[j, half*64 : half*64+64] (64 regs) and
// Whh[j, half*32 : half*32+32] (32 regs) -> ~120 VGPR total, NO spill.
// half 0 reads x1 / h[0:32]; half 1 reads x2 / h[32:64] (cat split at k=64).
// Partial sums combine via LDS. Two nodes per barrier iteration.
__global__ __launch_bounds__(384) void layer_kernel(
    const float* __restrict__ X1, const float* __restrict__ X2,
    const float* __restrict__ H,
    const float* __restrict__ Wg,  const float* __restrict__ bg,
    const float* __restrict__ Whh, const float* __restrict__ bhh,
    float* __restrict__ Hout)
{
    const int t    = threadIdx.x;
    const int j    = (t < 192) ? t : (t - 192);
    const int half = (t < 192) ? 0 : 1;

    float Wgr[64];
    #pragma unroll
    for (int k=0;k<64;k+=4) {
        float4 v = *(const float4*)&Wg[j*128 + half*64 + k];
        Wgr[k]=v.x; Wgr[k+1]=v.y; Wgr[k+2]=v.z; Wgr[k+3]=v.w;
    }
    float Whr[32];
    #pragma unroll
    for (int k=0;k<32;k+=4) {
        float4 v = *(const float4*)&Whh[j*64 + half*32 + k];
        Whr[k]=v.x; Whr[k+1]=v.y; Whr[k+2]=v.z; Whr[k+3]=v.w;
    }
    const float bgj = (half==0) ? bg[j]  : 0.0f;
    const float bhj = (half==0) ? bhh[j] : 0.0f;

    __shared__ float gi_s[2][2][192];   // [node][half][j]
    __shared__ float gh_s[2][2][192];

    for (int n0 = blockIdx.x*2; n0 + 1 < NN; n0 += gridDim.x*2) {
        float giA = bgj, ghA = bhj;
        float giB = 0.f, ghB = 0.f;
        const float* Xh = half ? X2 : X1;
        const float4* xA = (const float4*)&Xh[(long)n0*HH];
        const float4* xB = (const float4*)&Xh[(long)(n0+1)*HH];
        const float4* hA4 = (const float4*)&H[(long)n0*HH     + half*32];
        const float4* hB4 = (const float4*)&H[(long)(n0+1)*HH + half*32];
        #pragma unroll
        for (int k4=0;k4<16;++k4) {
            float4 a = xA[k4];
            float4 b = xB[k4];
            giA += a.x*Wgr[4*k4] + a.y*Wgr[4*k4+1] + a.z*Wgr[4*k4+2] + a.w*Wgr[4*k4+3];
            giB += b.x*Wgr[4*k4] + b.y*Wgr[4*k4+1] + b.z*Wgr[4*k4+2] + b.w*Wgr[4*k4+3];
        }
        #pragma unroll
        for (int k4=0;k4<8;++k4) {
            float4 a = hA4[k4];
            float4 b = hB4[k4];
            ghA += a.x*Whr[4*k4] + a.y*Whr[4*k4+1] + a.z*Whr[4*k4+2] + a.w*Whr[4*k4+3];
            ghB += b.x*Whr[4*k4] + b.y*Whr[4*k4+1] + b.z*Whr[4*k4+2] + b.w*Whr[4*k4+3];
        }
        gi_s[0][half][j] = giA;  gh_s[0][half][j] = ghA;
        gi_s[1][half][j] = giB;  gh_s[1][half][j] = ghB;
        __syncthreads();
        if (t < 128) {
            int nd = t >> 6;          // 0 or 1
            int jj = t & 63;
            int n  = n0 + nd;
            float gr = gi_s[nd][0][jj]     + gi_s[nd][1][jj];
            float hr = gh_s[nd][0][jj]     + gh_s[nd][1][jj];
            float gz = gi_s[nd][0][jj+64]  + gi_s[nd][1][jj+64];
            float hz = gh_s[nd][0][jj+64]  + gh_s[nd][1][jj+64];
            float gn = gi_s[nd][0][jj+128] + gi_s[nd][1][jj+128];
            float hn = gh_s[nd][0][jj+128] + gh_s[nd][1][jj+128];
            float r  = fsig(gr + hr);
            float z  = fsig(gz + hz);
            float nv = ftanh(gn + r*hn);
            float hv = H[(long)n*HH + jj];
            Hout[(long)n*HH + jj] = (1.0f - z)*nv + z*hv;
        }
        __syncthreads();
    }
}

// ---- y = x @ W^T + b (64->64). Safe to run in place (only the owning wave reads row n).
__global__ __launch_bounds__(256) void lin64_kernel(
    const float* X, const float* __restrict__ W,
    const float* __restrict__ b, float* Y)
{
    const int j   = threadIdx.x & 63;
    const int sub = threadIdx.x >> 6;
    float Wr[64];
    #pragma unroll
    for (int k=0;k<64;k+=4) {
        float4 v = *(const float4*)&W[j*64+k];
        Wr[k]=v.x; Wr[k+1]=v.y; Wr[k+2]=v.z; Wr[k+3]=v.w;
    }
    const float bj = b[j];
    for (int n0 = blockIdx.x*4; n0 < NN; n0 += gridDim.x*4) {
        int n = n0 + sub;
        float acc = bj;
        const float4* xr = (const float4*)&X[(long)n*HH];
        #pragma unroll
        for (int k4=0;k4<16;++k4) {
            float4 v = xr[k4];
            acc += v.x*Wr[4*k4] + v.y*Wr[4*k4+1] + v.z*Wr[4*k4+2] + v.w*Wr[4*k4+3];
        }
        Y[(long)n*HH + j] = acc;
    }
}

// ---- out = log_softmax(h2 @ W_out^T + b_out). 16 lanes per node; shfl reduce width 16.
__global__ __launch_bounds__(256) void out_kernel(
    const float* __restrict__ X, const float* __restrict__ W,
    const float* __restrict__ b, float* __restrict__ Y)
{
    const int c   = threadIdx.x & 15;
    const int sub = threadIdx.x >> 4;   // 16 nodes per block-iteration
    float Wr[64];
    #pragma unroll
    for (int k=0;k<64;k+=4) {
        float4 v = *(const float4*)&W[c*64+k];
        Wr[k]=v.x; Wr[k+1]=v.y; Wr[k+2]=v.z; Wr[k+3]=v.w;
    }
    const float bc = b[c];
    for (int n0 = blockIdx.x*16; n0 < NN; n0 += gridDim.x*16) {
        int n = n0 + sub;
        float acc = bc;
        const float4* xr = (const float4*)&X[(long)n*HH];
        #pragma unroll
        for (int k4=0;k4<16;++k4) {
            float4 v = xr[k4];
            acc += v.x*Wr[4*k4] + v.y*Wr[4*k4+1] + v.z*Wr[4*k4+2] + v.w*Wr[4*k4+3];
        }
        float m = acc;
        #pragma unroll
        for (int off=8; off>0; off>>=1) m = fmaxf(m, __shfl_xor(m, off, 16));
        float ex = __expf(acc - m);
        float s = ex;
        #pragma unroll
        for (int off=8; off>0; off>>=1) s += __shfl_xor(s, off, 16);
        Y[(long)n*CC + c] = acc - m - __logf(s);
    }
}

extern "C" void kernel_launch(void* const* d_in, const int* in_sizes, int n_in,
                              void* d_out, int out_size, void* d_ws, size_t ws_size,
                              hipStream_t stream)
{
    const float* x       = (const float*)d_in[0];
    const int*   ei      = (const int*)  d_in[1];
    const float* ew      = (const float*)d_in[2];
    const int*   ei_re   = (const int*)  d_in[3];
    const float* ew_re   = (const float*)d_in[4];
    const float* W_first = (const float*)d_in[5];
    const float* b_first = (const float*)d_in[6];
    const float* W_con1  = (const float*)d_in[7];
    const float* b_con1  = (const float*)d_in[8];
    const float* W_con2  = (const float*)d_in[9];
    const float* b_con2  = (const float*)d_in[10];
    const float* W_lin1  = (const float*)d_in[11];
    const float* b_lin1  = (const float*)d_in[12];
    const float* W_out   = (const float*)d_in[13];
    const float* b_out   = (const float*)d_in[14];
    const float* W_ih    = (const float*)d_in[15];
    const float* W_hh    = (const float*)d_in[16];
    const float* b_ih    = (const float*)d_in[17];
    const float* b_hh    = (const float*)d_in[18];
    float* out = (float*)d_out;

    float* h  = (float*)d_ws;              // [N,64]
    float* x1 = h  + (long)NN*HH;          // [N,64]
    float* x2 = x1 + (long)NN*HH;          // [N,64]
    float* hA = x2 + (long)NN*HH;          // [N,64] gate output / lin1 in-place / h2
    float* W1 = hA + (long)NN*HH;          // [192,128]
    float* W2 = W1 + 192*128;
    float* b1 = W2 + 192*128;
    float* b2 = b1 + 192;

    // 0) combined weights (needed before layer kernels only)
    precomp_kernel<<<(192*128 + 192 + 255)/256, 256, 0, stream>>>(
        W_ih, b_ih, W_con1, b_con1, W_con2, b_con2, W1, b1, W2, b2);

    // 1) h = x @ W_first^T + b_first
    lin_first_kernel<<<2048, 256, 0, stream>>>(x, W_first, b_first, h);

    // 2) layer-1 propagation
    hipMemsetAsync(x1, 0, (size_t)2*NN*HH*sizeof(float), stream);
    prop_kernel<<<EE/4, 256, 0, stream>>>(h, ei,    ew,    x1);
    prop_kernel<<<EE/4, 256, 0, stream>>>(h, ei_re, ew_re, x2);

    // 3) fused con1 + GRU -> hA
    layer_kernel<<<1536, 384, 0, stream>>>(x1, x2, h, W1, b1, W_hh, b_hh, hA);

    // 4) lin1 (in place on hA)
    lin64_kernel<<<2048, 256, 0, stream>>>(hA, W_lin1, b_lin1, hA);

    // 5) layer-2 propagation
    hipMemsetAsync(x1, 0, (size_t)2*NN*HH*sizeof(float), stream);
    prop_kernel<<<EE/4, 256, 0, stream>>>(hA, ei,    ew,    x1);
    prop_kernel<<<EE/4, 256, 0, stream>>>(hA, ei_re, ew_re, x2);

    // 6) fused con2 + GRU -> hA
    layer_kernel<<<1536, 384, 0, stream>>>(x1, x2, h, W2, b2, W_hh, b_hh, hA);

    // 7) W_out + log_softmax
    out_kernel<<<2048, 256, 0, stream>>>(hA, W_out, b_out, out);
}

// Round 3
// 1316.017 us; speedup vs baseline: 2.2138x; 2.2138x over previous
//
#include <hip/hip_runtime.h>

#define NN 100000
#define FF 128
#define HH 64
#define CC 16
#define EE 1000000

typedef __bf16 bf16;
typedef __attribute__((ext_vector_type(8))) __bf16 bf16x8;
typedef __attribute__((ext_vector_type(4))) __bf16 bf16x4;
typedef __attribute__((ext_vector_type(4))) float f32x4;

__device__ __forceinline__ float fsig(float t)  { return 1.0f/(1.0f+__expf(-t)); }
__device__ __forceinline__ float ftanh(float t) { return 1.0f - 2.0f/(__expf(2.0f*t)+1.0f); }

// ---- Combined weights, emitted in bf16 for the MFMA layer kernel:
//  W1bf/W2bf [192][128] = bf16(W_ih @ W_con{1,2});  b1/b2 [192] fp32 = b_ih + W_ih@b_con
//  Whbf [192][64] = bf16(W_hh)
__global__ void precomp_kernel(const float* __restrict__ W_ih, const float* __restrict__ b_ih,
                               const float* __restrict__ Wc1,  const float* __restrict__ bc1,
                               const float* __restrict__ Wc2,  const float* __restrict__ bc2,
                               const float* __restrict__ W_hh,
                               bf16* __restrict__ W1bf, float* __restrict__ b1,
                               bf16* __restrict__ W2bf, float* __restrict__ b2,
                               bf16* __restrict__ Whbf)
{
    int idx = blockIdx.x*blockDim.x + threadIdx.x;
    const int total = 192*128;
    if (idx < total) {
        int j = idx >> 7, k = idx & 127;
        float s1 = 0.f, s2 = 0.f;
        for (int m=0; m<64; ++m) {
            float wih = W_ih[j*64+m];
            s1 += wih * Wc1[m*128+k];
            s2 += wih * Wc2[m*128+k];
        }
        W1bf[idx] = (bf16)s1; W2bf[idx] = (bf16)s2;
    } else if (idx < total + 192) {
        int j = idx - total;
        float s1 = b_ih[j], s2 = b_ih[j];
        for (int m=0; m<64; ++m) {
            float wih = W_ih[j*64+m];
            s1 += wih * bc1[m];
            s2 += wih * bc2[m];
        }
        b1[j] = s1; b2[j] = s2;
    } else if (idx < total + 192 + 192*64) {
        int i = idx - (total + 192);
        Whbf[i] = (bf16)W_hh[i];
    }
}

// ---- h = x @ W_first^T + b   (K=128 -> M=64). Thread j holds W row j in VGPRs.
__global__ __launch_bounds__(256) void lin_first_kernel(
    const float* __restrict__ X, const float* __restrict__ W,
    const float* __restrict__ b, float* __restrict__ Y)
{
    const int j   = threadIdx.x & 63;
    const int sub = threadIdx.x >> 6;   // 4 nodes per block-iteration
    float Wr[128];
    #pragma unroll
    for (int k=0;k<128;k+=4) {
        float4 v = *(const float4*)&W[j*128+k];
        Wr[k]=v.x; Wr[k+1]=v.y; Wr[k+2]=v.z; Wr[k+3]=v.w;
    }
    const float bj = b[j];
    for (int n0 = blockIdx.x*4; n0 < NN; n0 += gridDim.x*4) {
        int n = n0 + sub;
        float acc = bj;
        const float4* xr = (const float4*)&X[(long)n*FF];
        #pragma unroll
        for (int k4=0;k4<32;++k4) {
            float4 v = xr[k4];
            acc += v.x*Wr[4*k4] + v.y*Wr[4*k4+1] + v.z*Wr[4*k4+2] + v.w*Wr[4*k4+3];
        }
        Y[(long)n*HH + j] = acc;
    }
}

// ---- segment_sum scatter: out[dst] += X[src]*w. One wave per edge, lane = feature.
__global__ __launch_bounds__(256) void prop_kernel(
    const float* __restrict__ X, const int* __restrict__ ei,
    const float* __restrict__ w, float* __restrict__ out)
{
    int e    = blockIdx.x*4 + (threadIdx.x>>6);
    int lane = threadIdx.x & 63;
    if (e >= EE) return;
    int   src = ei[e];
    int   dst = ei[EE + e];
    float wt  = w[e];
    float v = X[(long)src*HH + lane] * wt;
    atomicAdd(&out[(long)dst*HH + lane], v);
}

// ---- fused layer v3 (MFMA bf16):
// Per 32-node tile: gi[192] = [x1|x2] @ Wg^T (K=128), gh[192] = h @ Whh^T (K=64),
// then GRU gates -> Hout. 256 threads = 4 waves; wave w owns gate columns
// [16w,16w+16) via J-tiles {16w, 64+16w, 128+16w} for BOTH gi and gh, so all six
// gate operands for a (node,col) sit in the same lane -> gates fully in-register.
// B-fragments are explicit bf16x8 vector regs loaded once per block (no spillable
// arrays). A-tile staged in LDS (32 x 200 bf16, pad balances banks).
__global__ __launch_bounds__(256, 2) void layer_mfma_kernel(
    const float* __restrict__ X1, const float* __restrict__ X2,
    const float* __restrict__ H,
    const bf16* __restrict__ Wg, const float* __restrict__ bg,
    const bf16* __restrict__ Wh, const float* __restrict__ bh,
    float* __restrict__ Hout)
{
    const int t    = threadIdx.x;
    const int w    = t >> 6;
    const int lane = t & 63;
    const int col  = lane & 15;
    const int quad = lane >> 4;

    // B fragments: lane holds W[J][k..k+8) where J = jbase + col (B-operand layout)
    bf16x8 Bg[3][4];
    bf16x8 Bh[3][2];
    float bgv[3], bhv[3];
    #pragma unroll
    for (int jt=0; jt<3; ++jt) {
        int J = jt*64 + 16*w + col;
        #pragma unroll
        for (int ks=0; ks<4; ++ks)
            Bg[jt][ks] = *(const bf16x8*)&Wg[J*128 + ks*32 + quad*8];
        #pragma unroll
        for (int ks=0; ks<2; ++ks)
            Bh[jt][ks] = *(const bf16x8*)&Wh[J*64 + ks*32 + quad*8];
        bgv[jt] = bg[J];
        bhv[jt] = bh[J];
    }

    __shared__ bf16 Alds[32][200];   // rows: [x1(64)|x2(64)|h(64)], pad to 200

    const int m_st = t >> 3;        // staging: thread owns row m_st
    const int c_in = t & 7;         // and chunks c_in + 8*it (it=0..5)

    for (int tb = blockIdx.x*32; tb < NN; tb += gridDim.x*32) {
        // ---- stage A-tile (fp32 -> bf16)
        {
            long n = tb + m_st;
            const float4* rx1 = (const float4*)&X1[n*HH];
            const float4* rx2 = (const float4*)&X2[n*HH];
            const float4* rh  = (const float4*)&H [n*HH];
            #pragma unroll
            for (int it=0; it<6; ++it) {
                int cc = c_in + it*8;          // 0..47 (4-float chunk in row)
                float4 v = (cc < 16) ? rx1[cc] : (cc < 32) ? rx2[cc-16] : rh[cc-32];
                bf16x4 bv = { (bf16)v.x, (bf16)v.y, (bf16)v.z, (bf16)v.w };
                *(bf16x4*)&Alds[m_st][cc*4] = bv;
            }
        }
        __syncthreads();

        f32x4 accg[2][3];
        f32x4 acch[2][3];
        #pragma unroll
        for (int mt=0; mt<2; ++mt)
            #pragma unroll
            for (int jt=0; jt<3; ++jt) {
                accg[mt][jt] = (f32x4){0.f,0.f,0.f,0.f};
                acch[mt][jt] = (f32x4){0.f,0.f,0.f,0.f};
            }

        // gi: K = 0..127 (x1|x2)
        #pragma unroll
        for (int ks=0; ks<4; ++ks) {
            #pragma unroll
            for (int mt=0; mt<2; ++mt) {
                bf16x8 a = *(const bf16x8*)&Alds[mt*16 + col][ks*32 + quad*8];
                #pragma unroll
                for (int jt=0; jt<3; ++jt)
                    accg[mt][jt] = __builtin_amdgcn_mfma_f32_16x16x32_bf16(
                        a, Bg[jt][ks], accg[mt][jt], 0, 0, 0);
            }
        }
        // gh: K = 128..191 (h)
        #pragma unroll
        for (int ks=0; ks<2; ++ks) {
            #pragma unroll
            for (int mt=0; mt<2; ++mt) {
                bf16x8 a = *(const bf16x8*)&Alds[mt*16 + col][128 + ks*32 + quad*8];
                #pragma unroll
                for (int jt=0; jt<3; ++jt)
                    acch[mt][jt] = __builtin_amdgcn_mfma_f32_16x16x32_bf16(
                        a, Bh[jt][ks], acch[mt][jt], 0, 0, 0);
            }
        }
        __syncthreads();   // A-tile reads done before next stage overwrites

        // ---- gates, fully in-register (C/D layout: col=lane&15, row=quad*4+reg)
        const int c = 16*w + col;
        #pragma unroll
        for (int mt=0; mt<2; ++mt) {
            #pragma unroll
            for (int r=0; r<4; ++r) {
                long n = tb + mt*16 + quad*4 + r;
                float gr = accg[mt][0][r] + bgv[0];
                float gz = accg[mt][1][r] + bgv[1];
                float gn = accg[mt][2][r] + bgv[2];
                float hr = acch[mt][0][r] + bhv[0];
                float hz = acch[mt][1][r] + bhv[1];
                float hn = acch[mt][2][r] + bhv[2];
                float rr = fsig(gr + hr);
                float zz = fsig(gz + hz);
                float nv = ftanh(gn + rr*hn);
                float hv = H[n*HH + c];
                Hout[n*HH + c] = (1.0f - zz)*nv + zz*hv;
            }
        }
    }
}

// ---- y = x @ W^T + b (64->64). Safe to run in place (only the owning wave reads row n).
__global__ __launch_bounds__(256) void lin64_kernel(
    const float* X, const float* __restrict__ W,
    const float* __restrict__ b, float* Y)
{
    const int j   = threadIdx.x & 63;
    const int sub = threadIdx.x >> 6;
    float Wr[64];
    #pragma unroll
    for (int k=0;k<64;k+=4) {
        float4 v = *(const float4*)&W[j*64+k];
        Wr[k]=v.x; Wr[k+1]=v.y; Wr[k+2]=v.z; Wr[k+3]=v.w;
    }
    const float bj = b[j];
    for (int n0 = blockIdx.x*4; n0 < NN; n0 += gridDim.x*4) {
        int n = n0 + sub;
        float acc = bj;
        const float4* xr = (const float4*)&X[(long)n*HH];
        #pragma unroll
        for (int k4=0;k4<16;++k4) {
            float4 v = xr[k4];
            acc += v.x*Wr[4*k4] + v.y*Wr[4*k4+1] + v.z*Wr[4*k4+2] + v.w*Wr[4*k4+3];
        }
        Y[(long)n*HH + j] = acc;
    }
}

// ---- out = log_softmax(h2 @ W_out^T + b_out). 16 lanes per node; shfl reduce width 16.
__global__ __launch_bounds__(256) void out_kernel(
    const float* __restrict__ X, const float* __restrict__ W,
    const float* __restrict__ b, float* __restrict__ Y)
{
    const int c   = threadIdx.x & 15;
    const int sub = threadIdx.x >> 4;   // 16 nodes per block-iteration
    float Wr[64];
    #pragma unroll
    for (int k=0;k<64;k+=4) {
        float4 v = *(const float4*)&W[c*64+k];
        Wr[k]=v.x; Wr[k+1]=v.y; Wr[k+2]=v.z; Wr[k+3]=v.w;
    }
    const float bc = b[c];
    for (int n0 = blockIdx.x*16; n0 < NN; n0 += gridDim.x*16) {
        int n = n0 + sub;
        float acc = bc;
        const float4* xr = (const float4*)&X[(long)n*HH];
        #pragma unroll
        for (int k4=0;k4<16;++k4) {
            float4 v = xr[k4];
            acc += v.x*Wr[4*k4] + v.y*Wr[4*k4+1] + v.z*Wr[4*k4+2] + v.w*Wr[4*k4+3];
        }
        float m = acc;
        #pragma unroll
        for (int off=8; off>0; off>>=1) m = fmaxf(m, __shfl_xor(m, off, 16));
        float ex = __expf(acc - m);
        float s = ex;
        #pragma unroll
        for (int off=8; off>0; off>>=1) s += __shfl_xor(s, off, 16);
        Y[(long)n*CC + c] = acc - m - __logf(s);
    }
}

extern "C" void kernel_launch(void* const* d_in, const int* in_sizes, int n_in,
                              void* d_out, int out_size, void* d_ws, size_t ws_size,
                              hipStream_t stream)
{
    const float* x       = (const float*)d_in[0];
    const int*   ei      = (const int*)  d_in[1];
    const float* ew      = (const float*)d_in[2];
    const int*   ei_re   = (const int*)  d_in[3];
    const float* ew_re   = (const float*)d_in[4];
    const float* W_first = (const float*)d_in[5];
    const float* b_first = (const float*)d_in[6];
    const float* W_con1  = (const float*)d_in[7];
    const float* b_con1  = (const float*)d_in[8];
    const float* W_con2  = (const float*)d_in[9];
    const float* b_con2  = (const float*)d_in[10];
    const float* W_lin1  = (const float*)d_in[11];
    const float* b_lin1  = (const float*)d_in[12];
    const float* W_out   = (const float*)d_in[13];
    const float* b_out   = (const float*)d_in[14];
    const float* W_ih    = (const float*)d_in[15];
    const float* W_hh    = (const float*)d_in[16];
    const float* b_ih    = (const float*)d_in[17];
    const float* b_hh    = (const float*)d_in[18];
    float* out = (float*)d_out;

    float* h  = (float*)d_ws;              // [N,64]
    float* x1 = h  + (long)NN*HH;          // [N,64]
    float* x2 = x1 + (long)NN*HH;          // [N,64]
    float* hA = x2 + (long)NN*HH;          // [N,64] gate output / lin1 in-place / h2
    float* b1 = hA + (long)NN*HH;          // [192]
    float* b2 = b1 + 192;                  // [192]
    bf16*  W1bf = (bf16*)(b2 + 192);       // [192*128]
    bf16*  W2bf = W1bf + 192*128;          // [192*128]
    bf16*  Whbf = W2bf + 192*128;          // [192*64]

    // 0) combined weights in bf16 (+ fp32 biases)
    precomp_kernel<<<(192*128 + 192 + 192*64 + 255)/256, 256, 0, stream>>>(
        W_ih, b_ih, W_con1, b_con1, W_con2, b_con2, W_hh,
        W1bf, b1, W2bf, b2, Whbf);

    // 1) h = x @ W_first^T + b_first
    lin_first_kernel<<<2048, 256, 0, stream>>>(x, W_first, b_first, h);

    // 2) layer-1 propagation
    hipMemsetAsync(x1, 0, (size_t)2*NN*HH*sizeof(float), stream);
    prop_kernel<<<EE/4, 256, 0, stream>>>(h, ei,    ew,    x1);
    prop_kernel<<<EE/4, 256, 0, stream>>>(h, ei_re, ew_re, x2);

    // 3) fused con1 + GRU -> hA   (MFMA)
    layer_mfma_kernel<<<1024, 256, 0, stream>>>(x1, x2, h, W1bf, b1, Whbf, b_hh, hA);

    // 4) lin1 (in place on hA)
    lin64_kernel<<<2048, 256, 0, stream>>>(hA, W_lin1, b_lin1, hA);

    // 5) layer-2 propagation
    hipMemsetAsync(x1, 0, (size_t)2*NN*HH*sizeof(float), stream);
    prop_kernel<<<EE/4, 256, 0, stream>>>(hA, ei,    ew,    x1);
    prop_kernel<<<EE/4, 256, 0, stream>>>(hA, ei_re, ew_re, x2);

    // 6) fused con2 + GRU -> hA   (MFMA)
    layer_mfma_kernel<<<1024, 256, 0, stream>>>(x1, x2, h, W2bf, b2, Whbf, b_hh, hA);

    // 7) W_out + log_softmax
    out_kernel<<<2048, 256, 0, stream>>>(hA, W_out, b_out, out);
}

// Round 4
// 851.096 us; speedup vs baseline: 3.4231x; 1.5463x over previous
//
#include <hip/hip_runtime.h>

#define NN 100000
#define FF 128
#define HH 64
#define CC 16
#define EE 1000000
#define NSEG (2*NN)                 // segments: [0,NN) = fwd, [NN,2NN) = rev
#define NBLK ((NSEG + 255) / 256)   // scan blocks = 782

typedef __bf16 bf16;
typedef __attribute__((ext_vector_type(8))) __bf16 bf16x8;
typedef __attribute__((ext_vector_type(4))) __bf16 bf16x4;
typedef __attribute__((ext_vector_type(4))) float f32x4;

__device__ __forceinline__ float fsig(float t)  { return 1.0f/(1.0f+__expf(-t)); }
__device__ __forceinline__ float ftanh(float t) { return 1.0f - 2.0f/(__expf(2.0f*t)+1.0f); }

// ---- Combined weights, emitted in bf16 for the MFMA layer kernel
__global__ void precomp_kernel(const float* __restrict__ W_ih, const float* __restrict__ b_ih,
                               const float* __restrict__ Wc1,  const float* __restrict__ bc1,
                               const float* __restrict__ Wc2,  const float* __restrict__ bc2,
                               const float* __restrict__ W_hh,
                               bf16* __restrict__ W1bf, float* __restrict__ b1,
                               bf16* __restrict__ W2bf, float* __restrict__ b2,
                               bf16* __restrict__ Whbf)
{
    int idx = blockIdx.x*blockDim.x + threadIdx.x;
    const int total = 192*128;
    if (idx < total) {
        int j = idx >> 7, k = idx & 127;
        float s1 = 0.f, s2 = 0.f;
        for (int m=0; m<64; ++m) {
            float wih = W_ih[j*64+m];
            s1 += wih * Wc1[m*128+k];
            s2 += wih * Wc2[m*128+k];
        }
        W1bf[idx] = (bf16)s1; W2bf[idx] = (bf16)s2;
    } else if (idx < total + 192) {
        int j = idx - total;
        float s1 = b_ih[j], s2 = b_ih[j];
        for (int m=0; m<64; ++m) {
            float wih = W_ih[j*64+m];
            s1 += wih * bc1[m];
            s2 += wih * bc2[m];
        }
        b1[j] = s1; b2[j] = s2;
    } else if (idx < total + 192 + 192*64) {
        int i = idx - (total + 192);
        Whbf[i] = (bf16)W_hh[i];
    }
}

// ================= CSR build (once per launch, used by both layers) =================

// counts: cnt[dst] (fwd) and cnt[NN+dst] (rev)
__global__ __launch_bounds__(256) void count_kernel(const int* __restrict__ ei,
                                                    const int* __restrict__ ei_re,
                                                    int* __restrict__ cnt)
{
    int idx = blockIdx.x*256 + threadIdx.x;
    if (idx < EE)            atomicAdd(&cnt[ei[EE+idx]], 1);
    else if (idx < 2*EE) {   int j = idx-EE; atomicAdd(&cnt[NN + ei_re[EE+j]], 1); }
}

// per-256-block exclusive scan + block totals
__global__ __launch_bounds__(256) void scanA_kernel(const int* __restrict__ cnt,
                                                    int* __restrict__ tmp,
                                                    int* __restrict__ bsum)
{
    __shared__ int sd[256];
    int t = threadIdx.x;
    int i = blockIdx.x*256 + t;
    int v = (i < NSEG) ? cnt[i] : 0;
    sd[t] = v;
    __syncthreads();
    #pragma unroll
    for (int off=1; off<256; off<<=1) {
        int x = (t>=off) ? sd[t-off] : 0;
        __syncthreads();
        if (t>=off) sd[t] += x;
        __syncthreads();
    }
    if (i < NSEG) tmp[i] = sd[t] - v;      // exclusive within block
    if (t == 255) bsum[blockIdx.x] = sd[255];
}

// exclusive scan of block totals (NBLK <= 1024)
__global__ __launch_bounds__(1024) void scanB_kernel(const int* __restrict__ bsum,
                                                     int* __restrict__ bscan)
{
    __shared__ int sd[1024];
    int t = threadIdx.x;
    int v = (t < NBLK) ? bsum[t] : 0;
    sd[t] = v;
    __syncthreads();
    #pragma unroll
    for (int off=1; off<1024; off<<=1) {
        int x = (t>=off) ? sd[t-off] : 0;
        __syncthreads();
        if (t>=off) sd[t] += x;
        __syncthreads();
    }
    if (t < NBLK) bscan[t] = sd[t] - v;
}

// combine -> row_ptr, and init fill cursors
__global__ __launch_bounds__(256) void scanC_kernel(const int* __restrict__ tmp,
                                                    const int* __restrict__ bscan,
                                                    int* __restrict__ rp,
                                                    int* __restrict__ cur)
{
    int i = blockIdx.x*256 + threadIdx.x;
    if (i < NSEG) { int v = tmp[i] + bscan[i>>8]; rp[i] = v; cur[i] = v; }
    if (i == 0) rp[NSEG] = 2*EE;
}

// scatter (src, w) into dst-sorted arrays
__global__ __launch_bounds__(256) void fill_kernel(const int* __restrict__ ei,
                                                   const float* __restrict__ ew,
                                                   const int* __restrict__ ei_re,
                                                   const float* __restrict__ ew_re,
                                                   int* __restrict__ cur,
                                                   int* __restrict__ col,
                                                   float* __restrict__ wv)
{
    int idx = blockIdx.x*256 + threadIdx.x;
    int d, s; float w;
    if (idx < EE)            { d = ei[EE+idx];            s = ei[idx];    w = ew[idx]; }
    else if (idx < 2*EE)     { int j = idx-EE; d = NN + ei_re[EE+j]; s = ei_re[j]; w = ew_re[j]; }
    else return;
    int p = atomicAdd(&cur[d], 1);
    col[p] = s; wv[p] = w;
}

// gather-based segment sum: one wave per segment; writes x1 (fwd) / x2 (rev)
__global__ __launch_bounds__(256) void csr_prop_kernel(const float* __restrict__ X,
    const int* __restrict__ rp, const int* __restrict__ col, const float* __restrict__ wv,
    float* __restrict__ x1, float* __restrict__ x2)
{
    int s = blockIdx.x*4 + (threadIdx.x>>6);
    if (s >= NSEG) return;
    int lane = threadIdx.x & 63;
    int e  = rp[s], e1 = rp[s+1];
    float acc = 0.f;
    for (; e+4 <= e1; e += 4) {
        int   c0=col[e],   c1=col[e+1], c2=col[e+2], c3=col[e+3];
        float w0=wv[e],    w1=wv[e+1],  w2=wv[e+2],  w3=wv[e+3];
        float v0=X[(long)c0*HH+lane], v1=X[(long)c1*HH+lane],
              v2=X[(long)c2*HH+lane], v3=X[(long)c3*HH+lane];
        acc += w0*v0; acc += w1*v1; acc += w2*v2; acc += w3*v3;
    }
    for (; e < e1; ++e) acc += wv[e]*X[(long)col[e]*HH+lane];
    float* o = (s < NN) ? &x1[(long)s*HH] : &x2[(long)(s-NN)*HH];
    o[lane] = acc;
}

// ================= dense kernels (unchanged from R3) =================

__global__ __launch_bounds__(256) void lin_first_kernel(
    const float* __restrict__ X, const float* __restrict__ W,
    const float* __restrict__ b, float* __restrict__ Y)
{
    const int j   = threadIdx.x & 63;
    const int sub = threadIdx.x >> 6;
    float Wr[128];
    #pragma unroll
    for (int k=0;k<128;k+=4) {
        float4 v = *(const float4*)&W[j*128+k];
        Wr[k]=v.x; Wr[k+1]=v.y; Wr[k+2]=v.z; Wr[k+3]=v.w;
    }
    const float bj = b[j];
    for (int n0 = blockIdx.x*4; n0 < NN; n0 += gridDim.x*4) {
        int n = n0 + sub;
        float acc = bj;
        const float4* xr = (const float4*)&X[(long)n*FF];
        #pragma unroll
        for (int k4=0;k4<32;++k4) {
            float4 v = xr[k4];
            acc += v.x*Wr[4*k4] + v.y*Wr[4*k4+1] + v.z*Wr[4*k4+2] + v.w*Wr[4*k4+3];
        }
        Y[(long)n*HH + j] = acc;
    }
}

__global__ __launch_bounds__(256, 2) void layer_mfma_kernel(
    const float* __restrict__ X1, const float* __restrict__ X2,
    const float* __restrict__ H,
    const bf16* __restrict__ Wg, const float* __restrict__ bg,
    const bf16* __restrict__ Wh, const float* __restrict__ bh,
    float* __restrict__ Hout)
{
    const int t    = threadIdx.x;
    const int w    = t >> 6;
    const int lane = t & 63;
    const int col  = lane & 15;
    const int quad = lane >> 4;

    bf16x8 Bg[3][4];
    bf16x8 Bh[3][2];
    float bgv[3], bhv[3];
    #pragma unroll
    for (int jt=0; jt<3; ++jt) {
        int J = jt*64 + 16*w + col;
        #pragma unroll
        for (int ks=0; ks<4; ++ks)
            Bg[jt][ks] = *(const bf16x8*)&Wg[J*128 + ks*32 + quad*8];
        #pragma unroll
        for (int ks=0; ks<2; ++ks)
            Bh[jt][ks] = *(const bf16x8*)&Wh[J*64 + ks*32 + quad*8];
        bgv[jt] = bg[J];
        bhv[jt] = bh[J];
    }

    __shared__ bf16 Alds[32][200];

    const int m_st = t >> 3;
    const int c_in = t & 7;

    for (int tb = blockIdx.x*32; tb < NN; tb += gridDim.x*32) {
        {
            long n = tb + m_st;
            const float4* rx1 = (const float4*)&X1[n*HH];
            const float4* rx2 = (const float4*)&X2[n*HH];
            const float4* rh  = (const float4*)&H [n*HH];
            #pragma unroll
            for (int it=0; it<6; ++it) {
                int cc = c_in + it*8;
                float4 v = (cc < 16) ? rx1[cc] : (cc < 32) ? rx2[cc-16] : rh[cc-32];
                bf16x4 bv = { (bf16)v.x, (bf16)v.y, (bf16)v.z, (bf16)v.w };
                *(bf16x4*)&Alds[m_st][cc*4] = bv;
            }
        }
        __syncthreads();

        f32x4 accg[2][3];
        f32x4 acch[2][3];
        #pragma unroll
        for (int mt=0; mt<2; ++mt)
            #pragma unroll
            for (int jt=0; jt<3; ++jt) {
                accg[mt][jt] = (f32x4){0.f,0.f,0.f,0.f};
                acch[mt][jt] = (f32x4){0.f,0.f,0.f,0.f};
            }

        #pragma unroll
        for (int ks=0; ks<4; ++ks) {
            #pragma unroll
            for (int mt=0; mt<2; ++mt) {
                bf16x8 a = *(const bf16x8*)&Alds[mt*16 + col][ks*32 + quad*8];
                #pragma unroll
                for (int jt=0; jt<3; ++jt)
                    accg[mt][jt] = __builtin_amdgcn_mfma_f32_16x16x32_bf16(
                        a, Bg[jt][ks], accg[mt][jt], 0, 0, 0);
            }
        }
        #pragma unroll
        for (int ks=0; ks<2; ++ks) {
            #pragma unroll
            for (int mt=0; mt<2; ++mt) {
                bf16x8 a = *(const bf16x8*)&Alds[mt*16 + col][128 + ks*32 + quad*8];
                #pragma unroll
                for (int jt=0; jt<3; ++jt)
                    acch[mt][jt] = __builtin_amdgcn_mfma_f32_16x16x32_bf16(
                        a, Bh[jt][ks], acch[mt][jt], 0, 0, 0);
            }
        }
        __syncthreads();

        const int c = 16*w + col;
        #pragma unroll
        for (int mt=0; mt<2; ++mt) {
            #pragma unroll
            for (int r=0; r<4; ++r) {
                long n = tb + mt*16 + quad*4 + r;
                float gr = accg[mt][0][r] + bgv[0];
                float gz = accg[mt][1][r] + bgv[1];
                float gn = accg[mt][2][r] + bgv[2];
                float hr = acch[mt][0][r] + bhv[0];
                float hz = acch[mt][1][r] + bhv[1];
                float hn = acch[mt][2][r] + bhv[2];
                float rr = fsig(gr + hr);
                float zz = fsig(gz + hz);
                float nv = ftanh(gn + rr*hn);
                float hv = H[n*HH + c];
                Hout[n*HH + c] = (1.0f - zz)*nv + zz*hv;
            }
        }
    }
}

__global__ __launch_bounds__(256) void lin64_kernel(
    const float* X, const float* __restrict__ W,
    const float* __restrict__ b, float* Y)
{
    const int j   = threadIdx.x & 63;
    const int sub = threadIdx.x >> 6;
    float Wr[64];
    #pragma unroll
    for (int k=0;k<64;k+=4) {
        float4 v = *(const float4*)&W[j*64+k];
        Wr[k]=v.x; Wr[k+1]=v.y; Wr[k+2]=v.z; Wr[k+3]=v.w;
    }
    const float bj = b[j];
    for (int n0 = blockIdx.x*4; n0 < NN; n0 += gridDim.x*4) {
        int n = n0 + sub;
        float acc = bj;
        const float4* xr = (const float4*)&X[(long)n*HH];
        #pragma unroll
        for (int k4=0;k4<16;++k4) {
            float4 v = xr[k4];
            acc += v.x*Wr[4*k4] + v.y*Wr[4*k4+1] + v.z*Wr[4*k4+2] + v.w*Wr[4*k4+3];
        }
        Y[(long)n*HH + j] = acc;
    }
}

__global__ __launch_bounds__(256) void out_kernel(
    const float* __restrict__ X, const float* __restrict__ W,
    const float* __restrict__ b, float* __restrict__ Y)
{
    const int c   = threadIdx.x & 15;
    const int sub = threadIdx.x >> 4;
    float Wr[64];
    #pragma unroll
    for (int k=0;k<64;k+=4) {
        float4 v = *(const float4*)&W[c*64+k];
        Wr[k]=v.x; Wr[k+1]=v.y; Wr[k+2]=v.z; Wr[k+3]=v.w;
    }
    const float bc = b[c];
    for (int n0 = blockIdx.x*16; n0 < NN; n0 += gridDim.x*16) {
        int n = n0 + sub;
        float acc = bc;
        const float4* xr = (const float4*)&X[(long)n*HH];
        #pragma unroll
        for (int k4=0;k4<16;++k4) {
            float4 v = xr[k4];
            acc += v.x*Wr[4*k4] + v.y*Wr[4*k4+1] + v.z*Wr[4*k4+2] + v.w*Wr[4*k4+3];
        }
        float m = acc;
        #pragma unroll
        for (int off=8; off>0; off>>=1) m = fmaxf(m, __shfl_xor(m, off, 16));
        float ex = __expf(acc - m);
        float s = ex;
        #pragma unroll
        for (int off=8; off>0; off>>=1) s += __shfl_xor(s, off, 16);
        Y[(long)n*CC + c] = acc - m - __logf(s);
    }
}

extern "C" void kernel_launch(void* const* d_in, const int* in_sizes, int n_in,
                              void* d_out, int out_size, void* d_ws, size_t ws_size,
                              hipStream_t stream)
{
    const float* x       = (const float*)d_in[0];
    const int*   ei      = (const int*)  d_in[1];
    const float* ew      = (const float*)d_in[2];
    const int*   ei_re   = (const int*)  d_in[3];
    const float* ew_re   = (const float*)d_in[4];
    const float* W_first = (const float*)d_in[5];
    const float* b_first = (const float*)d_in[6];
    const float* W_con1  = (const float*)d_in[7];
    const float* b_con1  = (const float*)d_in[8];
    const float* W_con2  = (const float*)d_in[9];
    const float* b_con2  = (const float*)d_in[10];
    const float* W_lin1  = (const float*)d_in[11];
    const float* b_lin1  = (const float*)d_in[12];
    const float* W_out   = (const float*)d_in[13];
    const float* b_out   = (const float*)d_in[14];
    const float* W_ih    = (const float*)d_in[15];
    const float* W_hh    = (const float*)d_in[16];
    const float* b_ih    = (const float*)d_in[17];
    const float* b_hh    = (const float*)d_in[18];
    float* out = (float*)d_out;

    float* h  = (float*)d_ws;              // [N,64]
    float* x1 = h  + (long)NN*HH;          // [N,64]
    float* x2 = x1 + (long)NN*HH;          // [N,64]
    float* hA = x2 + (long)NN*HH;          // [N,64]
    float* b1 = hA + (long)NN*HH;          // [192]
    float* b2 = b1 + 192;                  // [192]
    bf16*  W1bf = (bf16*)(b2 + 192);       // [192*128]
    bf16*  W2bf = W1bf + 192*128;          // [192*128]
    bf16*  Whbf = W2bf + 192*128;          // [192*64]
    int*   rp    = (int*)(Whbf + 192*64);  // [NSEG+1] counts -> row_ptr
    int*   cur   = rp + NSEG + 1;          // [NSEG]
    int*   tmp   = cur + NSEG;             // [NSEG]
    int*   bsum  = tmp + NSEG;             // [1024]
    int*   bscan = bsum + 1024;            // [1024]
    int*   colA  = bscan + 1024;           // [2E]
    float* wvA   = (float*)(colA + 2*EE);  // [2E]

    // 0) combined weights in bf16 (+ fp32 biases)
    precomp_kernel<<<(192*128 + 192 + 192*64 + 255)/256, 256, 0, stream>>>(
        W_ih, b_ih, W_con1, b_con1, W_con2, b_con2, W_hh,
        W1bf, b1, W2bf, b2, Whbf);

    // 1) CSR build (both directions in one structure; reused by both layers)
    hipMemsetAsync(rp, 0, (size_t)(NSEG+1)*sizeof(int), stream);
    count_kernel<<<(2*EE + 255)/256, 256, 0, stream>>>(ei, ei_re, rp);
    scanA_kernel<<<NBLK, 256, 0, stream>>>(rp, tmp, bsum);
    scanB_kernel<<<1, 1024, 0, stream>>>(bsum, bscan);
    scanC_kernel<<<NBLK, 256, 0, stream>>>(tmp, bscan, rp, cur);
    fill_kernel<<<(2*EE + 255)/256, 256, 0, stream>>>(ei, ew, ei_re, ew_re, cur, colA, wvA);

    // 2) h = x @ W_first^T + b_first
    lin_first_kernel<<<2048, 256, 0, stream>>>(x, W_first, b_first, h);

    // 3) layer-1 propagation (gather, both directions)
    csr_prop_kernel<<<(NSEG + 3)/4, 256, 0, stream>>>(h, rp, colA, wvA, x1, x2);

    // 4) fused con1 + GRU -> hA   (MFMA)
    layer_mfma_kernel<<<1024, 256, 0, stream>>>(x1, x2, h, W1bf, b1, Whbf, b_hh, hA);

    // 5) lin1 (in place on hA)
    lin64_kernel<<<2048, 256, 0, stream>>>(hA, W_lin1, b_lin1, hA);

    // 6) layer-2 propagation
    csr_prop_kernel<<<(NSEG + 3)/4, 256, 0, stream>>>(hA, rp, colA, wvA, x1, x2);

    // 7) fused con2 + GRU -> hA   (MFMA)
    layer_mfma_kernel<<<1024, 256, 0, stream>>>(x1, x2, h, W2bf, b2, Whbf, b_hh, hA);

    // 8) W_out + log_softmax
    out_kernel<<<2048, 256, 0, stream>>>(hA, W_out, b_out, out);
}

// Round 5
// 620.034 us; speedup vs baseline: 4.6987x; 1.3727x over previous
//
#include <hip/hip_runtime.h>

#define NN 100000
#define FF 128
#define HH 64
#define CC 16
#define EE 1000000
#define NSEG (2*NN)                 // segments: [0,NN) = fwd, [NN,2NN) = rev
#define NBLK ((NSEG + 255) / 256)   // scan blocks = 782

typedef __bf16 bf16;
typedef __attribute__((ext_vector_type(8))) __bf16 bf16x8;
typedef __attribute__((ext_vector_type(4))) __bf16 bf16x4;
typedef __attribute__((ext_vector_type(4))) float f32x4;

__device__ __forceinline__ float fsig(float t)  { return 1.0f/(1.0f+__expf(-t)); }
__device__ __forceinline__ float ftanh(float t) { return 1.0f - 2.0f/(__expf(2.0f*t)+1.0f); }

// ---- Combined weights in bf16 + bf16 copies of W_first / W_lin1 / W_out
__global__ void precomp_kernel(const float* __restrict__ W_ih, const float* __restrict__ b_ih,
                               const float* __restrict__ Wc1,  const float* __restrict__ bc1,
                               const float* __restrict__ Wc2,  const float* __restrict__ bc2,
                               const float* __restrict__ W_hh, const float* __restrict__ W_first,
                               const float* __restrict__ W_lin1, const float* __restrict__ W_out,
                               bf16* __restrict__ W1bf, float* __restrict__ b1,
                               bf16* __restrict__ W2bf, float* __restrict__ b2,
                               bf16* __restrict__ Whbf, bf16* __restrict__ Wfbf,
                               bf16* __restrict__ Wlbf, bf16* __restrict__ Wobf)
{
    int idx = blockIdx.x*blockDim.x + threadIdx.x;
    const int t0 = 192*128;          // W1/W2
    const int t1 = t0 + 192;         // b1/b2
    const int t2 = t1 + 192*64;      // Whbf
    const int t3 = t2 + 64*128;      // Wfbf
    const int t4 = t3 + 64*64;       // Wlbf
    const int t5 = t4 + 16*64;       // Wobf
    if (idx < t0) {
        int j = idx >> 7, k = idx & 127;
        float s1 = 0.f, s2 = 0.f;
        for (int m=0; m<64; ++m) {
            float wih = W_ih[j*64+m];
            s1 += wih * Wc1[m*128+k];
            s2 += wih * Wc2[m*128+k];
        }
        W1bf[idx] = (bf16)s1; W2bf[idx] = (bf16)s2;
    } else if (idx < t1) {
        int j = idx - t0;
        float s1 = b_ih[j], s2 = b_ih[j];
        for (int m=0; m<64; ++m) {
            float wih = W_ih[j*64+m];
            s1 += wih * bc1[m];
            s2 += wih * bc2[m];
        }
        b1[j] = s1; b2[j] = s2;
    } else if (idx < t2) {
        int i = idx - t1;  Whbf[i] = (bf16)W_hh[i];
    } else if (idx < t3) {
        int i = idx - t2;  Wfbf[i] = (bf16)W_first[i];
    } else if (idx < t4) {
        int i = idx - t3;  Wlbf[i] = (bf16)W_lin1[i];
    } else if (idx < t5) {
        int i = idx - t4;  Wobf[i] = (bf16)W_out[i];
    }
}

// ================= CSR build (once per launch, used by both layers) =================

__global__ __launch_bounds__(256) void count_kernel(const int* __restrict__ ei,
                                                    const int* __restrict__ ei_re,
                                                    int* __restrict__ cnt)
{
    int idx = blockIdx.x*256 + threadIdx.x;
    if (idx < EE)            atomicAdd(&cnt[ei[EE+idx]], 1);
    else if (idx < 2*EE) {   int j = idx-EE; atomicAdd(&cnt[NN + ei_re[EE+j]], 1); }
}

__global__ __launch_bounds__(256) void scanA_kernel(const int* __restrict__ cnt,
                                                    int* __restrict__ tmp,
                                                    int* __restrict__ bsum)
{
    __shared__ int sd[256];
    int t = threadIdx.x;
    int i = blockIdx.x*256 + t;
    int v = (i < NSEG) ? cnt[i] : 0;
    sd[t] = v;
    __syncthreads();
    #pragma unroll
    for (int off=1; off<256; off<<=1) {
        int x = (t>=off) ? sd[t-off] : 0;
        __syncthreads();
        if (t>=off) sd[t] += x;
        __syncthreads();
    }
    if (i < NSEG) tmp[i] = sd[t] - v;
    if (t == 255) bsum[blockIdx.x] = sd[255];
}

__global__ __launch_bounds__(1024) void scanB_kernel(const int* __restrict__ bsum,
                                                     int* __restrict__ bscan)
{
    __shared__ int sd[1024];
    int t = threadIdx.x;
    int v = (t < NBLK) ? bsum[t] : 0;
    sd[t] = v;
    __syncthreads();
    #pragma unroll
    for (int off=1; off<1024; off<<=1) {
        int x = (t>=off) ? sd[t-off] : 0;
        __syncthreads();
        if (t>=off) sd[t] += x;
        __syncthreads();
    }
    if (t < NBLK) bscan[t] = sd[t] - v;
}

__global__ __launch_bounds__(256) void scanC_kernel(const int* __restrict__ tmp,
                                                    const int* __restrict__ bscan,
                                                    int* __restrict__ rp,
                                                    int* __restrict__ cur)
{
    int i = blockIdx.x*256 + threadIdx.x;
    if (i < NSEG) { int v = tmp[i] + bscan[i>>8]; rp[i] = v; cur[i] = v; }
    if (i == 0) rp[NSEG] = 2*EE;
}

__global__ __launch_bounds__(256) void fill_kernel(const int* __restrict__ ei,
                                                   const float* __restrict__ ew,
                                                   const int* __restrict__ ei_re,
                                                   const float* __restrict__ ew_re,
                                                   int* __restrict__ cur,
                                                   int* __restrict__ col,
                                                   float* __restrict__ wv)
{
    int idx = blockIdx.x*256 + threadIdx.x;
    int d, s; float w;
    if (idx < EE)            { d = ei[EE+idx];            s = ei[idx];    w = ew[idx]; }
    else if (idx < 2*EE)     { int j = idx-EE; d = NN + ei_re[EE+j]; s = ei_re[j]; w = ew_re[j]; }
    else return;
    int p = atomicAdd(&cur[d], 1);
    col[p] = s; wv[p] = w;
}

__global__ __launch_bounds__(256) void csr_prop_kernel(const float* __restrict__ X,
    const int* __restrict__ rp, const int* __restrict__ col, const float* __restrict__ wv,
    float* __restrict__ x1, float* __restrict__ x2)
{
    int s = blockIdx.x*4 + (threadIdx.x>>6);
    if (s >= NSEG) return;
    int lane = threadIdx.x & 63;
    int e  = rp[s], e1 = rp[s+1];
    float acc = 0.f;
    for (; e+4 <= e1; e += 4) {
        int   c0=col[e],   c1=col[e+1], c2=col[e+2], c3=col[e+3];
        float w0=wv[e],    w1=wv[e+1],  w2=wv[e+2],  w3=wv[e+3];
        float v0=X[(long)c0*HH+lane], v1=X[(long)c1*HH+lane],
              v2=X[(long)c2*HH+lane], v3=X[(long)c3*HH+lane];
        acc += w0*v0; acc += w1*v1; acc += w2*v2; acc += w3*v3;
    }
    for (; e < e1; ++e) acc += wv[e]*X[(long)col[e]*HH+lane];
    float* o = (s < NN) ? &x1[(long)s*HH] : &x2[(long)(s-NN)*HH];
    o[lane] = acc;
}

// ================= dense kernels: all MFMA now =================

// h = x @ W_first^T + b.  M-tile 32, K=128. Wave w owns output cols [16w,16w+16).
__global__ __launch_bounds__(256, 2) void lin_first_mfma_kernel(
    const float* __restrict__ X, const bf16* __restrict__ Wf,
    const float* __restrict__ b, float* __restrict__ Y)
{
    const int t = threadIdx.x;
    const int w = t >> 6, lane = t & 63, col = lane & 15, quad = lane >> 4;
    bf16x8 B[4];
    #pragma unroll
    for (int ks=0; ks<4; ++ks)
        B[ks] = *(const bf16x8*)&Wf[(16*w+col)*128 + ks*32 + quad*8];
    const float bv = b[16*w + col];
    __shared__ bf16 Alds[32][136];
    const int m_st = t >> 3, c_in = t & 7;
    for (int tb = blockIdx.x*32; tb < NN; tb += gridDim.x*32) {
        const float4* rx = (const float4*)&X[(long)(tb+m_st)*FF];
        #pragma unroll
        for (int it=0; it<4; ++it) {
            int cc = c_in + it*8;
            float4 v = rx[cc];
            bf16x4 bvv = {(bf16)v.x,(bf16)v.y,(bf16)v.z,(bf16)v.w};
            *(bf16x4*)&Alds[m_st][cc*4] = bvv;
        }
        __syncthreads();
        f32x4 acc[2] = {{0.f,0.f,0.f,0.f},{0.f,0.f,0.f,0.f}};
        #pragma unroll
        for (int ks=0; ks<4; ++ks)
            #pragma unroll
            for (int mt=0; mt<2; ++mt) {
                bf16x8 a = *(const bf16x8*)&Alds[mt*16+col][ks*32+quad*8];
                acc[mt] = __builtin_amdgcn_mfma_f32_16x16x32_bf16(a, B[ks], acc[mt], 0,0,0);
            }
        __syncthreads();
        #pragma unroll
        for (int mt=0; mt<2; ++mt)
            #pragma unroll
            for (int r=0; r<4; ++r)
                Y[(long)(tb+mt*16+quad*4+r)*HH + 16*w+col] = acc[mt][r] + bv;
    }
}

// y = x @ W^T + b (64->64), in place safe (tile fully staged before writes).
__global__ __launch_bounds__(256, 2) void lin64_mfma_kernel(
    const float* X, const bf16* __restrict__ Wl,
    const float* __restrict__ b, float* Y)
{
    const int t = threadIdx.x;
    const int w = t >> 6, lane = t & 63, col = lane & 15, quad = lane >> 4;
    bf16x8 B[2];
    #pragma unroll
    for (int ks=0; ks<2; ++ks)
        B[ks] = *(const bf16x8*)&Wl[(16*w+col)*64 + ks*32 + quad*8];
    const float bv = b[16*w + col];
    __shared__ bf16 Alds[32][72];
    const int m_st = t >> 3, c_in = t & 7;
    for (int tb = blockIdx.x*32; tb < NN; tb += gridDim.x*32) {
        const float4* rx = (const float4*)&X[(long)(tb+m_st)*HH];
        #pragma unroll
        for (int it=0; it<2; ++it) {
            int cc = c_in + it*8;
            float4 v = rx[cc];
            bf16x4 bvv = {(bf16)v.x,(bf16)v.y,(bf16)v.z,(bf16)v.w};
            *(bf16x4*)&Alds[m_st][cc*4] = bvv;
        }
        __syncthreads();
        f32x4 acc[2] = {{0.f,0.f,0.f,0.f},{0.f,0.f,0.f,0.f}};
        #pragma unroll
        for (int ks=0; ks<2; ++ks)
            #pragma unroll
            for (int mt=0; mt<2; ++mt) {
                bf16x8 a = *(const bf16x8*)&Alds[mt*16+col][ks*32+quad*8];
                acc[mt] = __builtin_amdgcn_mfma_f32_16x16x32_bf16(a, B[ks], acc[mt], 0,0,0);
            }
        __syncthreads();
        #pragma unroll
        for (int mt=0; mt<2; ++mt)
            #pragma unroll
            for (int r=0; r<4; ++r)
                Y[(long)(tb+mt*16+quad*4+r)*HH + 16*w+col] = acc[mt][r] + bv;
    }
}

// out = log_softmax(h2 @ W_out^T + b_out). M-tile 128 (wave w -> rows [32w,32w+32)),
// J-tile = all 16 classes; logits for a node sit in an aligned 16-lane group.
__global__ __launch_bounds__(256) void out_mfma_kernel(
    const float* __restrict__ X, const bf16* __restrict__ Wo,
    const float* __restrict__ b, float* __restrict__ Y)
{
    const int t = threadIdx.x;
    const int w = t >> 6, lane = t & 63, col = lane & 15, quad = lane >> 4;
    bf16x8 B[2];
    #pragma unroll
    for (int ks=0; ks<2; ++ks)
        B[ks] = *(const bf16x8*)&Wo[col*64 + ks*32 + quad*8];
    const float bv = b[col];
    __shared__ bf16 Alds[128][72];
    const int r_st = t >> 1, sub = t & 1;
    const int tb = blockIdx.x*128;
    {
        const float4* rx = (const float4*)&X[(long)(tb+r_st)*HH];
        #pragma unroll
        for (int it=0; it<8; ++it) {
            int cc = sub*8 + it;
            float4 v = rx[cc];
            bf16x4 bvv = {(bf16)v.x,(bf16)v.y,(bf16)v.z,(bf16)v.w};
            *(bf16x4*)&Alds[r_st][cc*4] = bvv;
        }
    }
    __syncthreads();
    f32x4 acc[2] = {{0.f,0.f,0.f,0.f},{0.f,0.f,0.f,0.f}};
    #pragma unroll
    for (int ks=0; ks<2; ++ks)
        #pragma unroll
        for (int mt=0; mt<2; ++mt) {
            bf16x8 a = *(const bf16x8*)&Alds[w*32 + mt*16 + col][ks*32+quad*8];
            acc[mt] = __builtin_amdgcn_mfma_f32_16x16x32_bf16(a, B[ks], acc[mt], 0,0,0);
        }
    #pragma unroll
    for (int mt=0; mt<2; ++mt) {
        #pragma unroll
        for (int r=0; r<4; ++r) {
            int n = tb + w*32 + mt*16 + quad*4 + r;
            float val = acc[mt][r] + bv;
            float m = val;
            #pragma unroll
            for (int off=8; off>0; off>>=1) m = fmaxf(m, __shfl_xor(m, off, 16));
            float ex = __expf(val - m);
            float s = ex;
            #pragma unroll
            for (int off=8; off>0; off>>=1) s += __shfl_xor(s, off, 16);
            if (n < NN) Y[(long)n*CC + col] = val - m - __logf(s);
        }
    }
}

// fused con + GRU (unchanged from R3)
__global__ __launch_bounds__(256, 2) void layer_mfma_kernel(
    const float* __restrict__ X1, const float* __restrict__ X2,
    const float* __restrict__ H,
    const bf16* __restrict__ Wg, const float* __restrict__ bg,
    const bf16* __restrict__ Wh, const float* __restrict__ bh,
    float* __restrict__ Hout)
{
    const int t    = threadIdx.x;
    const int w    = t >> 6;
    const int lane = t & 63;
    const int col  = lane & 15;
    const int quad = lane >> 4;

    bf16x8 Bg[3][4];
    bf16x8 Bh[3][2];
    float bgv[3], bhv[3];
    #pragma unroll
    for (int jt=0; jt<3; ++jt) {
        int J = jt*64 + 16*w + col;
        #pragma unroll
        for (int ks=0; ks<4; ++ks)
            Bg[jt][ks] = *(const bf16x8*)&Wg[J*128 + ks*32 + quad*8];
        #pragma unroll
        for (int ks=0; ks<2; ++ks)
            Bh[jt][ks] = *(const bf16x8*)&Wh[J*64 + ks*32 + quad*8];
        bgv[jt] = bg[J];
        bhv[jt] = bh[J];
    }

    __shared__ bf16 Alds[32][200];

    const int m_st = t >> 3;
    const int c_in = t & 7;

    for (int tb = blockIdx.x*32; tb < NN; tb += gridDim.x*32) {
        {
            long n = tb + m_st;
            const float4* rx1 = (const float4*)&X1[n*HH];
            const float4* rx2 = (const float4*)&X2[n*HH];
            const float4* rh  = (const float4*)&H [n*HH];
            #pragma unroll
            for (int it=0; it<6; ++it) {
                int cc = c_in + it*8;
                float4 v = (cc < 16) ? rx1[cc] : (cc < 32) ? rx2[cc-16] : rh[cc-32];
                bf16x4 bv = { (bf16)v.x, (bf16)v.y, (bf16)v.z, (bf16)v.w };
                *(bf16x4*)&Alds[m_st][cc*4] = bv;
            }
        }
        __syncthreads();

        f32x4 accg[2][3];
        f32x4 acch[2][3];
        #pragma unroll
        for (int mt=0; mt<2; ++mt)
            #pragma unroll
            for (int jt=0; jt<3; ++jt) {
                accg[mt][jt] = (f32x4){0.f,0.f,0.f,0.f};
                acch[mt][jt] = (f32x4){0.f,0.f,0.f,0.f};
            }

        #pragma unroll
        for (int ks=0; ks<4; ++ks) {
            #pragma unroll
            for (int mt=0; mt<2; ++mt) {
                bf16x8 a = *(const bf16x8*)&Alds[mt*16 + col][ks*32 + quad*8];
                #pragma unroll
                for (int jt=0; jt<3; ++jt)
                    accg[mt][jt] = __builtin_amdgcn_mfma_f32_16x16x32_bf16(
                        a, Bg[jt][ks], accg[mt][jt], 0, 0, 0);
            }
        }
        #pragma unroll
        for (int ks=0; ks<2; ++ks) {
            #pragma unroll
            for (int mt=0; mt<2; ++mt) {
                bf16x8 a = *(const bf16x8*)&Alds[mt*16 + col][128 + ks*32 + quad*8];
                #pragma unroll
                for (int jt=0; jt<3; ++jt)
                    acch[mt][jt] = __builtin_amdgcn_mfma_f32_16x16x32_bf16(
                        a, Bh[jt][ks], acch[mt][jt], 0, 0, 0);
            }
        }
        __syncthreads();

        const int c = 16*w + col;
        #pragma unroll
        for (int mt=0; mt<2; ++mt) {
            #pragma unroll
            for (int r=0; r<4; ++r) {
                long n = tb + mt*16 + quad*4 + r;
                float gr = accg[mt][0][r] + bgv[0];
                float gz = accg[mt][1][r] + bgv[1];
                float gn = accg[mt][2][r] + bgv[2];
                float hr = acch[mt][0][r] + bhv[0];
                float hz = acch[mt][1][r] + bhv[1];
                float hn = acch[mt][2][r] + bhv[2];
                float rr = fsig(gr + hr);
                float zz = fsig(gz + hz);
                float nv = ftanh(gn + rr*hn);
                float hv = H[n*HH + c];
                Hout[n*HH + c] = (1.0f - zz)*nv + zz*hv;
            }
        }
    }
}

extern "C" void kernel_launch(void* const* d_in, const int* in_sizes, int n_in,
                              void* d_out, int out_size, void* d_ws, size_t ws_size,
                              hipStream_t stream)
{
    const float* x       = (const float*)d_in[0];
    const int*   ei      = (const int*)  d_in[1];
    const float* ew      = (const float*)d_in[2];
    const int*   ei_re   = (const int*)  d_in[3];
    const float* ew_re   = (const float*)d_in[4];
    const float* W_first = (const float*)d_in[5];
    const float* b_first = (const float*)d_in[6];
    const float* W_con1  = (const float*)d_in[7];
    const float* b_con1  = (const float*)d_in[8];
    const float* W_con2  = (const float*)d_in[9];
    const float* b_con2  = (const float*)d_in[10];
    const float* W_lin1  = (const float*)d_in[11];
    const float* b_lin1  = (const float*)d_in[12];
    const float* W_out   = (const float*)d_in[13];
    const float* b_out   = (const float*)d_in[14];
    const float* W_ih    = (const float*)d_in[15];
    const float* W_hh    = (const float*)d_in[16];
    const float* b_ih    = (const float*)d_in[17];
    const float* b_hh    = (const float*)d_in[18];
    float* out = (float*)d_out;

    float* h  = (float*)d_ws;              // [N,64]
    float* x1 = h  + (long)NN*HH;          // [N,64]
    float* x2 = x1 + (long)NN*HH;          // [N,64]
    float* hA = x2 + (long)NN*HH;          // [N,64]
    float* b1 = hA + (long)NN*HH;          // [192]
    float* b2 = b1 + 192;                  // [192]
    bf16*  W1bf = (bf16*)(b2 + 192);       // [192*128]
    bf16*  W2bf = W1bf + 192*128;          // [192*128]
    bf16*  Whbf = W2bf + 192*128;          // [192*64]
    bf16*  Wfbf = Whbf + 192*64;           // [64*128]
    bf16*  Wlbf = Wfbf + 64*128;           // [64*64]
    bf16*  Wobf = Wlbf + 64*64;            // [16*64]
    int*   rp    = (int*)(Wobf + 16*64);   // [NSEG+1]
    int*   cur   = rp + NSEG + 1;          // [NSEG]
    int*   tmp   = cur + NSEG;             // [NSEG]
    int*   bsum  = tmp + NSEG;             // [1024]
    int*   bscan = bsum + 1024;            // [1024]
    int*   colA  = bscan + 1024;           // [2E]
    float* wvA   = (float*)(colA + 2*EE);  // [2E]

    // 0) weights in bf16 (+ fp32 biases)
    precomp_kernel<<<(192*128 + 192 + 192*64 + 64*128 + 64*64 + 16*64 + 255)/256, 256, 0, stream>>>(
        W_ih, b_ih, W_con1, b_con1, W_con2, b_con2, W_hh, W_first, W_lin1, W_out,
        W1bf, b1, W2bf, b2, Whbf, Wfbf, Wlbf, Wobf);

    // 1) CSR build
    hipMemsetAsync(rp, 0, (size_t)(NSEG+1)*sizeof(int), stream);
    count_kernel<<<(2*EE + 255)/256, 256, 0, stream>>>(ei, ei_re, rp);
    scanA_kernel<<<NBLK, 256, 0, stream>>>(rp, tmp, bsum);
    scanB_kernel<<<1, 1024, 0, stream>>>(bsum, bscan);
    scanC_kernel<<<NBLK, 256, 0, stream>>>(tmp, bscan, rp, cur);
    fill_kernel<<<(2*EE + 255)/256, 256, 0, stream>>>(ei, ew, ei_re, ew_re, cur, colA, wvA);

    // 2) h = x @ W_first^T + b_first   (MFMA)
    lin_first_mfma_kernel<<<1024, 256, 0, stream>>>(x, Wfbf, b_first, h);

    // 3) layer-1 propagation (gather)
    csr_prop_kernel<<<(NSEG + 3)/4, 256, 0, stream>>>(h, rp, colA, wvA, x1, x2);

    // 4) fused con1 + GRU -> hA   (MFMA)
    layer_mfma_kernel<<<1024, 256, 0, stream>>>(x1, x2, h, W1bf, b1, Whbf, b_hh, hA);

    // 5) lin1 (in place, MFMA)
    lin64_mfma_kernel<<<1024, 256, 0, stream>>>(hA, Wlbf, b_lin1, hA);

    // 6) layer-2 propagation
    csr_prop_kernel<<<(NSEG + 3)/4, 256, 0, stream>>>(hA, rp, colA, wvA, x1, x2);

    // 7) fused con2 + GRU -> hA   (MFMA)
    layer_mfma_kernel<<<1024, 256, 0, stream>>>(x1, x2, h, W2bf, b2, Whbf, b_hh, hA);

    // 8) W_out + log_softmax   (MFMA)
    out_mfma_kernel<<<(NN + 127)/128, 256, 0, stream>>>(hA, Wobf, b_out, out);
}

// Round 6
// 601.354 us; speedup vs baseline: 4.8447x; 1.0311x over previous
//
#include <hip/hip_runtime.h>

#define NN 100000
#define FF 128
#define HH 64
#define CC 16
#define EE 1000000
#define NSEG (2*NN)                 // segments: [0,NN) = fwd, [NN,2NN) = rev
#define NBLK ((NSEG + 255) / 256)   // scan blocks = 782
#define FPASS 8                     // fill write-locality passes
#define SEGPP (NSEG / FPASS)        // segments per pass = 25000

typedef __bf16 bf16;
typedef __attribute__((ext_vector_type(8))) __bf16 bf16x8;
typedef __attribute__((ext_vector_type(4))) __bf16 bf16x4;
typedef __attribute__((ext_vector_type(4))) float f32x4;

__device__ __forceinline__ float fsig(float t)  { return 1.0f/(1.0f+__expf(-t)); }
__device__ __forceinline__ float ftanh(float t) { return 1.0f - 2.0f/(__expf(2.0f*t)+1.0f); }

// ---- Combined weights in bf16 + bf16 copies of W_first / W_lin1 / W_out
__global__ void precomp_kernel(const float* __restrict__ W_ih, const float* __restrict__ b_ih,
                               const float* __restrict__ Wc1,  const float* __restrict__ bc1,
                               const float* __restrict__ Wc2,  const float* __restrict__ bc2,
                               const float* __restrict__ W_hh, const float* __restrict__ W_first,
                               const float* __restrict__ W_lin1, const float* __restrict__ W_out,
                               bf16* __restrict__ W1bf, float* __restrict__ b1,
                               bf16* __restrict__ W2bf, float* __restrict__ b2,
                               bf16* __restrict__ Whbf, bf16* __restrict__ Wfbf,
                               bf16* __restrict__ Wlbf, bf16* __restrict__ Wobf)
{
    int idx = blockIdx.x*blockDim.x + threadIdx.x;
    const int t0 = 192*128;          // W1/W2
    const int t1 = t0 + 192;         // b1/b2
    const int t2 = t1 + 192*64;      // Whbf
    const int t3 = t2 + 64*128;      // Wfbf
    const int t4 = t3 + 64*64;       // Wlbf
    const int t5 = t4 + 16*64;       // Wobf
    if (idx < t0) {
        int j = idx >> 7, k = idx & 127;
        float s1 = 0.f, s2 = 0.f;
        for (int m=0; m<64; ++m) {
            float wih = W_ih[j*64+m];
            s1 += wih * Wc1[m*128+k];
            s2 += wih * Wc2[m*128+k];
        }
        W1bf[idx] = (bf16)s1; W2bf[idx] = (bf16)s2;
    } else if (idx < t1) {
        int j = idx - t0;
        float s1 = b_ih[j], s2 = b_ih[j];
        for (int m=0; m<64; ++m) {
            float wih = W_ih[j*64+m];
            s1 += wih * bc1[m];
            s2 += wih * bc2[m];
        }
        b1[j] = s1; b2[j] = s2;
    } else if (idx < t2) {
        int i = idx - t1;  Whbf[i] = (bf16)W_hh[i];
    } else if (idx < t3) {
        int i = idx - t2;  Wfbf[i] = (bf16)W_first[i];
    } else if (idx < t4) {
        int i = idx - t3;  Wlbf[i] = (bf16)W_lin1[i];
    } else if (idx < t5) {
        int i = idx - t4;  Wobf[i] = (bf16)W_out[i];
    }
}

// ================= CSR build (once per launch, used by both layers) =================

__global__ __launch_bounds__(256) void count_kernel(const int* __restrict__ ei,
                                                    const int* __restrict__ ei_re,
                                                    int* __restrict__ cnt)
{
    int idx = blockIdx.x*256 + threadIdx.x;
    if (idx < EE)            atomicAdd(&cnt[ei[EE+idx]], 1);
    else if (idx < 2*EE) {   int j = idx-EE; atomicAdd(&cnt[NN + ei_re[EE+j]], 1); }
}

__global__ __launch_bounds__(256) void scanA_kernel(const int* __restrict__ cnt,
                                                    int* __restrict__ tmp,
                                                    int* __restrict__ bsum)
{
    __shared__ int sd[256];
    int t = threadIdx.x;
    int i = blockIdx.x*256 + t;
    int v = (i < NSEG) ? cnt[i] : 0;
    sd[t] = v;
    __syncthreads();
    #pragma unroll
    for (int off=1; off<256; off<<=1) {
        int x = (t>=off) ? sd[t-off] : 0;
        __syncthreads();
        if (t>=off) sd[t] += x;
        __syncthreads();
    }
    if (i < NSEG) tmp[i] = sd[t] - v;
    if (t == 255) bsum[blockIdx.x] = sd[255];
}

__global__ __launch_bounds__(1024) void scanB_kernel(const int* __restrict__ bsum,
                                                     int* __restrict__ bscan)
{
    __shared__ int sd[1024];
    int t = threadIdx.x;
    int v = (t < NBLK) ? bsum[t] : 0;
    sd[t] = v;
    __syncthreads();
    #pragma unroll
    for (int off=1; off<1024; off<<=1) {
        int x = (t>=off) ? sd[t-off] : 0;
        __syncthreads();
        if (t>=off) sd[t] += x;
        __syncthreads();
    }
    if (t < NBLK) bscan[t] = sd[t] - v;
}

__global__ __launch_bounds__(256) void scanC_kernel(const int* __restrict__ tmp,
                                                    const int* __restrict__ bscan,
                                                    int* __restrict__ rp,
                                                    int* __restrict__ cur)
{
    int i = blockIdx.x*256 + threadIdx.x;
    if (i < NSEG) { int v = tmp[i] + bscan[i>>8]; rp[i] = v; cur[i] = v; }
    if (i == 0) rp[NSEG] = 2*EE;
}

// Binned fill: pass p (= idx / 2E) places only segments [p*SEGPP,(p+1)*SEGPP),
// confining the active write window to ~2 MB (L2-resident -> no write
// amplification). (src,w) packed into one 8 B int2 store.
__global__ __launch_bounds__(256) void fill_kernel(const int* __restrict__ ei,
                                                   const float* __restrict__ ew,
                                                   const int* __restrict__ ei_re,
                                                   const float* __restrict__ ew_re,
                                                   int* __restrict__ cur,
                                                   int2* __restrict__ edata)
{
    long idx = (long)blockIdx.x*256 + threadIdx.x;
    if (idx >= (long)FPASS*2*EE) return;
    int pass = (int)(idx / (2*EE));
    int e    = (int)(idx % (2*EE));
    int d;
    if (e < EE) d = ei[EE+e];
    else        d = NN + ei_re[EE + (e-EE)];
    if (d < pass*SEGPP || d >= (pass+1)*SEGPP) return;
    int s; float w;
    if (e < EE) { s = ei[e];      w = ew[e]; }
    else        { s = ei_re[e-EE]; w = ew_re[e-EE]; }
    int p = atomicAdd(&cur[d], 1);
    edata[p] = make_int2(s, __float_as_int(w));
}

__global__ __launch_bounds__(256) void csr_prop_kernel(const float* __restrict__ X,
    const int* __restrict__ rp, const int2* __restrict__ edata,
    float* __restrict__ x1, float* __restrict__ x2)
{
    int s = blockIdx.x*4 + (threadIdx.x>>6);
    if (s >= NSEG) return;
    int lane = threadIdx.x & 63;
    int e  = rp[s], e1 = rp[s+1];
    float acc = 0.f;
    for (; e+4 <= e1; e += 4) {
        int2 d0 = edata[e],   d1 = edata[e+1], d2 = edata[e+2], d3 = edata[e+3];
        float v0 = X[(long)d0.x*HH+lane], v1 = X[(long)d1.x*HH+lane],
              v2 = X[(long)d2.x*HH+lane], v3 = X[(long)d3.x*HH+lane];
        acc += __int_as_float(d0.y)*v0; acc += __int_as_float(d1.y)*v1;
        acc += __int_as_float(d2.y)*v2; acc += __int_as_float(d3.y)*v3;
    }
    for (; e < e1; ++e) {
        int2 dd = edata[e];
        acc += __int_as_float(dd.y)*X[(long)dd.x*HH+lane];
    }
    float* o = (s < NN) ? &x1[(long)s*HH] : &x2[(long)(s-NN)*HH];
    o[lane] = acc;
}

// ================= dense kernels: all MFMA =================

__global__ __launch_bounds__(256, 2) void lin_first_mfma_kernel(
    const float* __restrict__ X, const bf16* __restrict__ Wf,
    const float* __restrict__ b, float* __restrict__ Y)
{
    const int t = threadIdx.x;
    const int w = t >> 6, lane = t & 63, col = lane & 15, quad = lane >> 4;
    bf16x8 B[4];
    #pragma unroll
    for (int ks=0; ks<4; ++ks)
        B[ks] = *(const bf16x8*)&Wf[(16*w+col)*128 + ks*32 + quad*8];
    const float bv = b[16*w + col];
    __shared__ bf16 Alds[32][136];
    const int m_st = t >> 3, c_in = t & 7;
    for (int tb = blockIdx.x*32; tb < NN; tb += gridDim.x*32) {
        const float4* rx = (const float4*)&X[(long)(tb+m_st)*FF];
        #pragma unroll
        for (int it=0; it<4; ++it) {
            int cc = c_in + it*8;
            float4 v = rx[cc];
            bf16x4 bvv = {(bf16)v.x,(bf16)v.y,(bf16)v.z,(bf16)v.w};
            *(bf16x4*)&Alds[m_st][cc*4] = bvv;
        }
        __syncthreads();
        f32x4 acc[2] = {{0.f,0.f,0.f,0.f},{0.f,0.f,0.f,0.f}};
        #pragma unroll
        for (int ks=0; ks<4; ++ks)
            #pragma unroll
            for (int mt=0; mt<2; ++mt) {
                bf16x8 a = *(const bf16x8*)&Alds[mt*16+col][ks*32+quad*8];
                acc[mt] = __builtin_amdgcn_mfma_f32_16x16x32_bf16(a, B[ks], acc[mt], 0,0,0);
            }
        __syncthreads();
        #pragma unroll
        for (int mt=0; mt<2; ++mt)
            #pragma unroll
            for (int r=0; r<4; ++r)
                Y[(long)(tb+mt*16+quad*4+r)*HH + 16*w+col] = acc[mt][r] + bv;
    }
}

__global__ __launch_bounds__(256, 2) void lin64_mfma_kernel(
    const float* X, const bf16* __restrict__ Wl,
    const float* __restrict__ b, float* Y)
{
    const int t = threadIdx.x;
    const int w = t >> 6, lane = t & 63, col = lane & 15, quad = lane >> 4;
    bf16x8 B[2];
    #pragma unroll
    for (int ks=0; ks<2; ++ks)
        B[ks] = *(const bf16x8*)&Wl[(16*w+col)*64 + ks*32 + quad*8];
    const float bv = b[16*w + col];
    __shared__ bf16 Alds[32][72];
    const int m_st = t >> 3, c_in = t & 7;
    for (int tb = blockIdx.x*32; tb < NN; tb += gridDim.x*32) {
        const float4* rx = (const float4*)&X[(long)(tb+m_st)*HH];
        #pragma unroll
        for (int it=0; it<2; ++it) {
            int cc = c_in + it*8;
            float4 v = rx[cc];
            bf16x4 bvv = {(bf16)v.x,(bf16)v.y,(bf16)v.z,(bf16)v.w};
            *(bf16x4*)&Alds[m_st][cc*4] = bvv;
        }
        __syncthreads();
        f32x4 acc[2] = {{0.f,0.f,0.f,0.f},{0.f,0.f,0.f,0.f}};
        #pragma unroll
        for (int ks=0; ks<2; ++ks)
            #pragma unroll
            for (int mt=0; mt<2; ++mt) {
                bf16x8 a = *(const bf16x8*)&Alds[mt*16+col][ks*32+quad*8];
                acc[mt] = __builtin_amdgcn_mfma_f32_16x16x32_bf16(a, B[ks], acc[mt], 0,0,0);
            }
        __syncthreads();
        #pragma unroll
        for (int mt=0; mt<2; ++mt)
            #pragma unroll
            for (int r=0; r<4; ++r)
                Y[(long)(tb+mt*16+quad*4+r)*HH + 16*w+col] = acc[mt][r] + bv;
    }
}

__global__ __launch_bounds__(256) void out_mfma_kernel(
    const float* __restrict__ X, const bf16* __restrict__ Wo,
    const float* __restrict__ b, float* __restrict__ Y)
{
    const int t = threadIdx.x;
    const int w = t >> 6, lane = t & 63, col = lane & 15, quad = lane >> 4;
    bf16x8 B[2];
    #pragma unroll
    for (int ks=0; ks<2; ++ks)
        B[ks] = *(const bf16x8*)&Wo[col*64 + ks*32 + quad*8];
    const float bv = b[col];
    __shared__ bf16 Alds[128][72];
    const int r_st = t >> 1, sub = t & 1;
    const int tb = blockIdx.x*128;
    {
        const float4* rx = (const float4*)&X[(long)(tb+r_st)*HH];
        #pragma unroll
        for (int it=0; it<8; ++it) {
            int cc = sub*8 + it;
            float4 v = rx[cc];
            bf16x4 bvv = {(bf16)v.x,(bf16)v.y,(bf16)v.z,(bf16)v.w};
            *(bf16x4*)&Alds[r_st][cc*4] = bvv;
        }
    }
    __syncthreads();
    f32x4 acc[2] = {{0.f,0.f,0.f,0.f},{0.f,0.f,0.f,0.f}};
    #pragma unroll
    for (int ks=0; ks<2; ++ks)
        #pragma unroll
        for (int mt=0; mt<2; ++mt) {
            bf16x8 a = *(const bf16x8*)&Alds[w*32 + mt*16 + col][ks*32+quad*8];
            acc[mt] = __builtin_amdgcn_mfma_f32_16x16x32_bf16(a, B[ks], acc[mt], 0,0,0);
        }
    #pragma unroll
    for (int mt=0; mt<2; ++mt) {
        #pragma unroll
        for (int r=0; r<4; ++r) {
            int n = tb + w*32 + mt*16 + quad*4 + r;
            float val = acc[mt][r] + bv;
            float m = val;
            #pragma unroll
            for (int off=8; off>0; off>>=1) m = fmaxf(m, __shfl_xor(m, off, 16));
            float ex = __expf(val - m);
            float s = ex;
            #pragma unroll
            for (int off=8; off>0; off>>=1) s += __shfl_xor(s, off, 16);
            if (n < NN) Y[(long)n*CC + col] = val - m - __logf(s);
        }
    }
}

__global__ __launch_bounds__(256, 2) void layer_mfma_kernel(
    const float* __restrict__ X1, const float* __restrict__ X2,
    const float* __restrict__ H,
    const bf16* __restrict__ Wg, const float* __restrict__ bg,
    const bf16* __restrict__ Wh, const float* __restrict__ bh,
    float* __restrict__ Hout)
{
    const int t    = threadIdx.x;
    const int w    = t >> 6;
    const int lane = t & 63;
    const int col  = lane & 15;
    const int quad = lane >> 4;

    bf16x8 Bg[3][4];
    bf16x8 Bh[3][2];
    float bgv[3], bhv[3];
    #pragma unroll
    for (int jt=0; jt<3; ++jt) {
        int J = jt*64 + 16*w + col;
        #pragma unroll
        for (int ks=0; ks<4; ++ks)
            Bg[jt][ks] = *(const bf16x8*)&Wg[J*128 + ks*32 + quad*8];
        #pragma unroll
        for (int ks=0; ks<2; ++ks)
            Bh[jt][ks] = *(const bf16x8*)&Wh[J*64 + ks*32 + quad*8];
        bgv[jt] = bg[J];
        bhv[jt] = bh[J];
    }

    __shared__ bf16 Alds[32][200];

    const int m_st = t >> 3;
    const int c_in = t & 7;

    for (int tb = blockIdx.x*32; tb < NN; tb += gridDim.x*32) {
        {
            long n = tb + m_st;
            const float4* rx1 = (const float4*)&X1[n*HH];
            const float4* rx2 = (const float4*)&X2[n*HH];
            const float4* rh  = (const float4*)&H [n*HH];
            #pragma unroll
            for (int it=0; it<6; ++it) {
                int cc = c_in + it*8;
                float4 v = (cc < 16) ? rx1[cc] : (cc < 32) ? rx2[cc-16] : rh[cc-32];
                bf16x4 bv = { (bf16)v.x, (bf16)v.y, (bf16)v.z, (bf16)v.w };
                *(bf16x4*)&Alds[m_st][cc*4] = bv;
            }
        }
        __syncthreads();

        f32x4 accg[2][3];
        f32x4 acch[2][3];
        #pragma unroll
        for (int mt=0; mt<2; ++mt)
            #pragma unroll
            for (int jt=0; jt<3; ++jt) {
                accg[mt][jt] = (f32x4){0.f,0.f,0.f,0.f};
                acch[mt][jt] = (f32x4){0.f,0.f,0.f,0.f};
            }

        #pragma unroll
        for (int ks=0; ks<4; ++ks) {
            #pragma unroll
            for (int mt=0; mt<2; ++mt) {
                bf16x8 a = *(const bf16x8*)&Alds[mt*16 + col][ks*32 + quad*8];
                #pragma unroll
                for (int jt=0; jt<3; ++jt)
                    accg[mt][jt] = __builtin_amdgcn_mfma_f32_16x16x32_bf16(
                        a, Bg[jt][ks], accg[mt][jt], 0, 0, 0);
            }
        }
        #pragma unroll
        for (int ks=0; ks<2; ++ks) {
            #pragma unroll
            for (int mt=0; mt<2; ++mt) {
                bf16x8 a = *(const bf16x8*)&Alds[mt*16 + col][128 + ks*32 + quad*8];
                #pragma unroll
                for (int jt=0; jt<3; ++jt)
                    acch[mt][jt] = __builtin_amdgcn_mfma_f32_16x16x32_bf16(
                        a, Bh[jt][ks], acch[mt][jt], 0, 0, 0);
            }
        }
        __syncthreads();

        const int c = 16*w + col;
        #pragma unroll
        for (int mt=0; mt<2; ++mt) {
            #pragma unroll
            for (int r=0; r<4; ++r) {
                long n = tb + mt*16 + quad*4 + r;
                float gr = accg[mt][0][r] + bgv[0];
                float gz = accg[mt][1][r] + bgv[1];
                float gn = accg[mt][2][r] + bgv[2];
                float hr = acch[mt][0][r] + bhv[0];
                float hz = acch[mt][1][r] + bhv[1];
                float hn = acch[mt][2][r] + bhv[2];
                float rr = fsig(gr + hr);
                float zz = fsig(gz + hz);
                float nv = ftanh(gn + rr*hn);
                float hv = H[n*HH + c];
                Hout[n*HH + c] = (1.0f - zz)*nv + zz*hv;
            }
        }
    }
}

extern "C" void kernel_launch(void* const* d_in, const int* in_sizes, int n_in,
                              void* d_out, int out_size, void* d_ws, size_t ws_size,
                              hipStream_t stream)
{
    const float* x       = (const float*)d_in[0];
    const int*   ei      = (const int*)  d_in[1];
    const float* ew      = (const float*)d_in[2];
    const int*   ei_re   = (const int*)  d_in[3];
    const float* ew_re   = (const float*)d_in[4];
    const float* W_first = (const float*)d_in[5];
    const float* b_first = (const float*)d_in[6];
    const float* W_con1  = (const float*)d_in[7];
    const float* b_con1  = (const float*)d_in[8];
    const float* W_con2  = (const float*)d_in[9];
    const float* b_con2  = (const float*)d_in[10];
    const float* W_lin1  = (const float*)d_in[11];
    const float* b_lin1  = (const float*)d_in[12];
    const float* W_out   = (const float*)d_in[13];
    const float* b_out   = (const float*)d_in[14];
    const float* W_ih    = (const float*)d_in[15];
    const float* W_hh    = (const float*)d_in[16];
    const float* b_ih    = (const float*)d_in[17];
    const float* b_hh    = (const float*)d_in[18];
    float* out = (float*)d_out;

    float* h  = (float*)d_ws;              // [N,64]
    float* x1 = h  + (long)NN*HH;          // [N,64]
    float* x2 = x1 + (long)NN*HH;          // [N,64]
    float* hA = x2 + (long)NN*HH;          // [N,64]
    float* b1 = hA + (long)NN*HH;          // [192]
    float* b2 = b1 + 192;                  // [192]
    bf16*  W1bf = (bf16*)(b2 + 192);       // [192*128]
    bf16*  W2bf = W1bf + 192*128;          // [192*128]
    bf16*  Whbf = W2bf + 192*128;          // [192*64]
    bf16*  Wfbf = Whbf + 192*64;           // [64*128]
    bf16*  Wlbf = Wfbf + 64*128;           // [64*64]
    bf16*  Wobf = Wlbf + 64*64;            // [16*64]
    int*   rp    = (int*)(Wobf + 16*64);   // [NSEG+1]
    int*   cur   = rp + NSEG + 1;          // [NSEG]
    int*   tmp   = cur + NSEG;             // [NSEG]
    int*   bsum  = tmp + NSEG;             // [1024]
    int*   bscan = bsum + 1024;            // [1024]
    int2*  edataA = (int2*)(bscan + 1024); // [2E] packed (src, w)

    // 0) weights in bf16 (+ fp32 biases)
    precomp_kernel<<<(192*128 + 192 + 192*64 + 64*128 + 64*64 + 16*64 + 255)/256, 256, 0, stream>>>(
        W_ih, b_ih, W_con1, b_con1, W_con2, b_con2, W_hh, W_first, W_lin1, W_out,
        W1bf, b1, W2bf, b2, Whbf, Wfbf, Wlbf, Wobf);

    // 1) CSR build
    hipMemsetAsync(rp, 0, (size_t)(NSEG+1)*sizeof(int), stream);
    count_kernel<<<(2*EE + 255)/256, 256, 0, stream>>>(ei, ei_re, rp);
    scanA_kernel<<<NBLK, 256, 0, stream>>>(rp, tmp, bsum);
    scanB_kernel<<<1, 1024, 0, stream>>>(bsum, bscan);
    scanC_kernel<<<NBLK, 256, 0, stream>>>(tmp, bscan, rp, cur);
    fill_kernel<<<(FPASS*2*EE + 255)/256, 256, 0, stream>>>(ei, ew, ei_re, ew_re, cur, edataA);

    // 2) h = x @ W_first^T + b_first   (MFMA)
    lin_first_mfma_kernel<<<1024, 256, 0, stream>>>(x, Wfbf, b_first, h);

    // 3) layer-1 propagation (gather)
    csr_prop_kernel<<<(NSEG + 3)/4, 256, 0, stream>>>(h, rp, edataA, x1, x2);

    // 4) fused con1 + GRU -> hA   (MFMA)
    layer_mfma_kernel<<<1024, 256, 0, stream>>>(x1, x2, h, W1bf, b1, Whbf, b_hh, hA);

    // 5) lin1 (in place, MFMA)
    lin64_mfma_kernel<<<1024, 256, 0, stream>>>(hA, Wlbf, b_lin1, hA);

    // 6) layer-2 propagation
    csr_prop_kernel<<<(NSEG + 3)/4, 256, 0, stream>>>(hA, rp, edataA, x1, x2);

    // 7) fused con2 + GRU -> hA   (MFMA)
    layer_mfma_kernel<<<1024, 256, 0, stream>>>(x1, x2, h, W2bf, b2, Whbf, b_hh, hA);

    // 8) W_out + log_softmax   (MFMA)
    out_mfma_kernel<<<(NN + 127)/128, 256, 0, stream>>>(hA, Wobf, b_out, out);
}

// Round 7
// 563.417 us; speedup vs baseline: 5.1709x; 1.0673x over previous
//
#include <hip/hip_runtime.h>

#define NN 100000
#define FF 128
#define HH 64
#define CC 16
#define EE 1000000
#define NSEG (2*NN)                 // segments: [0,NN) = fwd, [NN,2NN) = rev
#define NBLK ((NSEG + 255) / 256)   // scan blocks = 782
#define BSH 11                      // bucket = d >> 11 (2048 dsts/bucket)
#define NBUK 98                     // ceil(NSEG / 2048)
#define EPB 4096                    // edges per fillA block
#define P1BLK ((2*EE + EPB - 1) / EPB)

typedef __bf16 bf16;
typedef __attribute__((ext_vector_type(8))) __bf16 bf16x8;
typedef __attribute__((ext_vector_type(4))) __bf16 bf16x4;
typedef __attribute__((ext_vector_type(4))) float f32x4;

__device__ __forceinline__ float fsig(float t)  { return 1.0f/(1.0f+__expf(-t)); }
__device__ __forceinline__ float ftanh(float t) { return 1.0f - 2.0f/(__expf(2.0f*t)+1.0f); }

// ---- Combined weights in bf16 + bf16 copies of W_first / W_lin1 / W_out
__global__ void precomp_kernel(const float* __restrict__ W_ih, const float* __restrict__ b_ih,
                               const float* __restrict__ Wc1,  const float* __restrict__ bc1,
                               const float* __restrict__ Wc2,  const float* __restrict__ bc2,
                               const float* __restrict__ W_hh, const float* __restrict__ W_first,
                               const float* __restrict__ W_lin1, const float* __restrict__ W_out,
                               bf16* __restrict__ W1bf, float* __restrict__ b1,
                               bf16* __restrict__ W2bf, float* __restrict__ b2,
                               bf16* __restrict__ Whbf, bf16* __restrict__ Wfbf,
                               bf16* __restrict__ Wlbf, bf16* __restrict__ Wobf)
{
    int idx = blockIdx.x*blockDim.x + threadIdx.x;
    const int t0 = 192*128;          // W1/W2
    const int t1 = t0 + 192;         // b1/b2
    const int t2 = t1 + 192*64;      // Whbf
    const int t3 = t2 + 64*128;      // Wfbf
    const int t4 = t3 + 64*64;       // Wlbf
    const int t5 = t4 + 16*64;       // Wobf
    if (idx < t0) {
        int j = idx >> 7, k = idx & 127;
        float s1 = 0.f, s2 = 0.f;
        for (int m=0; m<64; ++m) {
            float wih = W_ih[j*64+m];
            s1 += wih * Wc1[m*128+k];
            s2 += wih * Wc2[m*128+k];
        }
        W1bf[idx] = (bf16)s1; W2bf[idx] = (bf16)s2;
    } else if (idx < t1) {
        int j = idx - t0;
        float s1 = b_ih[j], s2 = b_ih[j];
        for (int m=0; m<64; ++m) {
            float wih = W_ih[j*64+m];
            s1 += wih * bc1[m];
            s2 += wih * bc2[m];
        }
        b1[j] = s1; b2[j] = s2;
    } else if (idx < t2) {
        int i = idx - t1;  Whbf[i] = (bf16)W_hh[i];
    } else if (idx < t3) {
        int i = idx - t2;  Wfbf[i] = (bf16)W_first[i];
    } else if (idx < t4) {
        int i = idx - t3;  Wlbf[i] = (bf16)W_lin1[i];
    } else if (idx < t5) {
        int i = idx - t4;  Wobf[i] = (bf16)W_out[i];
    }
}

// ================= CSR build =================

__global__ __launch_bounds__(256) void count_kernel(const int* __restrict__ ei,
                                                    const int* __restrict__ ei_re,
                                                    int* __restrict__ cnt)
{
    int idx = blockIdx.x*256 + threadIdx.x;
    if (idx < EE)            atomicAdd(&cnt[ei[EE+idx]], 1);
    else if (idx < 2*EE) {   int j = idx-EE; atomicAdd(&cnt[NN + ei_re[EE+j]], 1); }
}

__global__ __launch_bounds__(256) void scanA_kernel(const int* __restrict__ cnt,
                                                    int* __restrict__ tmp,
                                                    int* __restrict__ bsum)
{
    __shared__ int sd[256];
    int t = threadIdx.x;
    int i = blockIdx.x*256 + t;
    int v = (i < NSEG) ? cnt[i] : 0;
    sd[t] = v;
    __syncthreads();
    #pragma unroll
    for (int off=1; off<256; off<<=1) {
        int x = (t>=off) ? sd[t-off] : 0;
        __syncthreads();
        if (t>=off) sd[t] += x;
        __syncthreads();
    }
    if (i < NSEG) tmp[i] = sd[t] - v;
    if (t == 255) bsum[blockIdx.x] = sd[255];
}

__global__ __launch_bounds__(1024) void scanB_kernel(const int* __restrict__ bsum,
                                                     int* __restrict__ bscan)
{
    __shared__ int sd[1024];
    int t = threadIdx.x;
    int v = (t < NBLK) ? bsum[t] : 0;
    sd[t] = v;
    __syncthreads();
    #pragma unroll
    for (int off=1; off<1024; off<<=1) {
        int x = (t>=off) ? sd[t-off] : 0;
        __syncthreads();
        if (t>=off) sd[t] += x;
        __syncthreads();
    }
    if (t < NBLK) bscan[t] = sd[t] - v;
}

// combine -> row_ptr; init per-bucket phase-A cursors
__global__ __launch_bounds__(256) void scanC_kernel(const int* __restrict__ tmp,
                                                    const int* __restrict__ bscan,
                                                    int* __restrict__ rp,
                                                    int* __restrict__ bkcur)
{
    int i = blockIdx.x*256 + threadIdx.x;
    if (i < NSEG) {
        int v = tmp[i] + bscan[i>>8];
        rp[i] = v;
        if ((i & ((1<<BSH)-1)) == 0) bkcur[i>>BSH] = v;
    }
    if (i == 0) rp[NSEG] = 2*EE;
}

// Phase A: bucket edges by coarse dst range. Per block: LDS histogram over
// NBUK buckets -> one global atomic per bucket -> contiguous per-block runs
// in each bucket region (each output line written by ONE block -> no
// cross-XCD partial-line writebacks).
__global__ __launch_bounds__(256) void fillA_kernel(const int* __restrict__ ei,
                                                    const float* __restrict__ ew,
                                                    const int* __restrict__ ei_re,
                                                    const float* __restrict__ ew_re,
                                                    int* __restrict__ bkcur,
                                                    int* __restrict__ tmp_d,
                                                    int2* __restrict__ tmp_e)
{
    __shared__ int hist[NBUK];
    __shared__ int base[NBUK];
    const int t = threadIdx.x;
    for (int i=t; i<NBUK; i+=256) hist[i] = 0;
    __syncthreads();
    const long e0 = (long)blockIdx.x * EPB;
    int pr[16];
    #pragma unroll
    for (int it=0; it<16; ++it) {
        long e = e0 + it*256 + t;
        int d = -1;
        if (e < EE)          d = ei[EE + e];
        else if (e < 2*EE)   d = NN + ei_re[EE + (e - EE)];
        if (d >= 0) {
            int b = d >> BSH;
            int r = atomicAdd(&hist[b], 1);
            pr[it] = (b << 16) | r;
        } else pr[it] = -1;
    }
    __syncthreads();
    for (int i=t; i<NBUK; i+=256) base[i] = atomicAdd(&bkcur[i], hist[i]);
    __syncthreads();
    #pragma unroll
    for (int it=0; it<16; ++it) {
        if (pr[it] < 0) continue;
        long e = e0 + it*256 + t;
        int d, s; float w;
        if (e < EE) { d = ei[EE+e]; s = ei[e]; w = ew[e]; }
        else { long j = e - EE; d = NN + ei_re[EE+j]; s = ei_re[j]; w = ew_re[j]; }
        int pos = base[pr[it] >> 16] + (pr[it] & 0xFFFF);
        tmp_d[pos] = d;
        tmp_e[pos] = make_int2(s, __float_as_int(w));
    }
}

// Phase B: one block per bucket. Dst cursors in LDS (fast atomics); scattered
// writes confined to this bucket's ~160 KB output window from ONE block.
__global__ __launch_bounds__(1024) void fillB_kernel(const int* __restrict__ rp,
                                                     const int* __restrict__ tmp_d,
                                                     const int2* __restrict__ tmp_e,
                                                     int2* __restrict__ edata)
{
    __shared__ int curL[1 << BSH];
    const int b  = blockIdx.x;
    const int d0 = b << BSH;
    const int dn = min(1 << BSH, NSEG - d0);
    const int p0 = rp[d0];
    const int p1 = rp[min(d0 + (1 << BSH), NSEG)];
    for (int i=threadIdx.x; i<dn; i+=1024) curL[i] = rp[d0 + i];
    __syncthreads();
    for (int pos = p0 + threadIdx.x; pos < p1; pos += 1024) {
        int d   = tmp_d[pos];
        int2 sw = tmp_e[pos];
        int p = atomicAdd(&curL[d - d0], 1);
        edata[p] = sw;
    }
}

// gather-based segment sum, bf16 source rows (128 B/edge), bf16 outputs
__global__ __launch_bounds__(256) void csr_prop_kernel(const bf16* __restrict__ X,
    const int* __restrict__ rp, const int2* __restrict__ edata,
    bf16* __restrict__ x1, bf16* __restrict__ x2)
{
    int s = blockIdx.x*4 + (threadIdx.x>>6);
    if (s >= NSEG) return;
    int lane = threadIdx.x & 63;
    int e  = rp[s], e1 = rp[s+1];
    float acc = 0.f;
    for (; e+4 <= e1; e += 4) {
        int2 d0 = edata[e],   d1 = edata[e+1], d2 = edata[e+2], d3 = edata[e+3];
        float v0 = (float)X[(long)d0.x*HH+lane], v1 = (float)X[(long)d1.x*HH+lane],
              v2 = (float)X[(long)d2.x*HH+lane], v3 = (float)X[(long)d3.x*HH+lane];
        acc += __int_as_float(d0.y)*v0; acc += __int_as_float(d1.y)*v1;
        acc += __int_as_float(d2.y)*v2; acc += __int_as_float(d3.y)*v3;
    }
    for (; e < e1; ++e) {
        int2 dd = edata[e];
        acc += __int_as_float(dd.y)*(float)X[(long)dd.x*HH+lane];
    }
    bf16* o = (s < NN) ? &x1[(long)s*HH] : &x2[(long)(s-NN)*HH];
    o[lane] = (bf16)acc;
}

// ================= dense kernels: all MFMA =================

// h = x @ W_first^T + b; writes fp32 h (GRU state) AND bf16 hbf (prop input)
__global__ __launch_bounds__(256, 2) void lin_first_mfma_kernel(
    const float* __restrict__ X, const bf16* __restrict__ Wf,
    const float* __restrict__ b, float* __restrict__ Y, bf16* __restrict__ Ybf)
{
    const int t = threadIdx.x;
    const int w = t >> 6, lane = t & 63, col = lane & 15, quad = lane >> 4;
    bf16x8 B[4];
    #pragma unroll
    for (int ks=0; ks<4; ++ks)
        B[ks] = *(const bf16x8*)&Wf[(16*w+col)*128 + ks*32 + quad*8];
    const float bv = b[16*w + col];
    __shared__ bf16 Alds[32][136];
    const int m_st = t >> 3, c_in = t & 7;
    for (int tb = blockIdx.x*32; tb < NN; tb += gridDim.x*32) {
        const float4* rx = (const float4*)&X[(long)(tb+m_st)*FF];
        #pragma unroll
        for (int it=0; it<4; ++it) {
            int cc = c_in + it*8;
            float4 v = rx[cc];
            bf16x4 bvv = {(bf16)v.x,(bf16)v.y,(bf16)v.z,(bf16)v.w};
            *(bf16x4*)&Alds[m_st][cc*4] = bvv;
        }
        __syncthreads();
        f32x4 acc[2] = {{0.f,0.f,0.f,0.f},{0.f,0.f,0.f,0.f}};
        #pragma unroll
        for (int ks=0; ks<4; ++ks)
            #pragma unroll
            for (int mt=0; mt<2; ++mt) {
                bf16x8 a = *(const bf16x8*)&Alds[mt*16+col][ks*32+quad*8];
                acc[mt] = __builtin_amdgcn_mfma_f32_16x16x32_bf16(a, B[ks], acc[mt], 0,0,0);
            }
        __syncthreads();
        #pragma unroll
        for (int mt=0; mt<2; ++mt)
            #pragma unroll
            for (int r=0; r<4; ++r) {
                long n = tb + mt*16 + quad*4 + r;
                float val = acc[mt][r] + bv;
                Y  [n*HH + 16*w+col] = val;
                Ybf[n*HH + 16*w+col] = (bf16)val;
            }
    }
}

// y = x @ W^T + b (64->64); output bf16 only (sole consumer is csr_prop)
__global__ __launch_bounds__(256, 2) void lin64_mfma_kernel(
    const float* __restrict__ X, const bf16* __restrict__ Wl,
    const float* __restrict__ b, bf16* __restrict__ Ybf)
{
    const int t = threadIdx.x;
    const int w = t >> 6, lane = t & 63, col = lane & 15, quad = lane >> 4;
    bf16x8 B[2];
    #pragma unroll
    for (int ks=0; ks<2; ++ks)
        B[ks] = *(const bf16x8*)&Wl[(16*w+col)*64 + ks*32 + quad*8];
    const float bv = b[16*w + col];
    __shared__ bf16 Alds[32][72];
    const int m_st = t >> 3, c_in = t & 7;
    for (int tb = blockIdx.x*32; tb < NN; tb += gridDim.x*32) {
        const float4* rx = (const float4*)&X[(long)(tb+m_st)*HH];
        #pragma unroll
        for (int it=0; it<2; ++it) {
            int cc = c_in + it*8;
            float4 v = rx[cc];
            bf16x4 bvv = {(bf16)v.x,(bf16)v.y,(bf16)v.z,(bf16)v.w};
            *(bf16x4*)&Alds[m_st][cc*4] = bvv;
        }
        __syncthreads();
        f32x4 acc[2] = {{0.f,0.f,0.f,0.f},{0.f,0.f,0.f,0.f}};
        #pragma unroll
        for (int ks=0; ks<2; ++ks)
            #pragma unroll
            for (int mt=0; mt<2; ++mt) {
                bf16x8 a = *(const bf16x8*)&Alds[mt*16+col][ks*32+quad*8];
                acc[mt] = __builtin_amdgcn_mfma_f32_16x16x32_bf16(a, B[ks], acc[mt], 0,0,0);
            }
        __syncthreads();
        #pragma unroll
        for (int mt=0; mt<2; ++mt)
            #pragma unroll
            for (int r=0; r<4; ++r)
                Ybf[(long)(tb+mt*16+quad*4+r)*HH + 16*w+col] = (bf16)(acc[mt][r] + bv);
    }
}

__global__ __launch_bounds__(256) void out_mfma_kernel(
    const float* __restrict__ X, const bf16* __restrict__ Wo,
    const float* __restrict__ b, float* __restrict__ Y)
{
    const int t = threadIdx.x;
    const int w = t >> 6, lane = t & 63, col = lane & 15, quad = lane >> 4;
    bf16x8 B[2];
    #pragma unroll
    for (int ks=0; ks<2; ++ks)
        B[ks] = *(const bf16x8*)&Wo[col*64 + ks*32 + quad*8];
    const float bv = b[col];
    __shared__ bf16 Alds[128][72];
    const int r_st = t >> 1, sub = t & 1;
    const int tb = blockIdx.x*128;
    {
        const float4* rx = (const float4*)&X[(long)(tb+r_st)*HH];
        #pragma unroll
        for (int it=0; it<8; ++it) {
            int cc = sub*8 + it;
            float4 v = rx[cc];
            bf16x4 bvv = {(bf16)v.x,(bf16)v.y,(bf16)v.z,(bf16)v.w};
            *(bf16x4*)&Alds[r_st][cc*4] = bvv;
        }
    }
    __syncthreads();
    f32x4 acc[2] = {{0.f,0.f,0.f,0.f},{0.f,0.f,0.f,0.f}};
    #pragma unroll
    for (int ks=0; ks<2; ++ks)
        #pragma unroll
        for (int mt=0; mt<2; ++mt) {
            bf16x8 a = *(const bf16x8*)&Alds[w*32 + mt*16 + col][ks*32+quad*8];
            acc[mt] = __builtin_amdgcn_mfma_f32_16x16x32_bf16(a, B[ks], acc[mt], 0,0,0);
        }
    #pragma unroll
    for (int mt=0; mt<2; ++mt) {
        #pragma unroll
        for (int r=0; r<4; ++r) {
            int n = tb + w*32 + mt*16 + quad*4 + r;
            float val = acc[mt][r] + bv;
            float m = val;
            #pragma unroll
            for (int off=8; off>0; off>>=1) m = fmaxf(m, __shfl_xor(m, off, 16));
            float ex = __expf(val - m);
            float s = ex;
            #pragma unroll
            for (int off=8; off>0; off>>=1) s += __shfl_xor(s, off, 16);
            if (n < NN) Y[(long)n*CC + col] = val - m - __logf(s);
        }
    }
}

// fused con + GRU; x1/x2 now bf16 inputs, h stays fp32 (GRU state precision)
__global__ __launch_bounds__(256, 2) void layer_mfma_kernel(
    const bf16* __restrict__ X1, const bf16* __restrict__ X2,
    const float* __restrict__ H,
    const bf16* __restrict__ Wg, const float* __restrict__ bg,
    const bf16* __restrict__ Wh, const float* __restrict__ bh,
    float* __restrict__ Hout)
{
    const int t    = threadIdx.x;
    const int w    = t >> 6;
    const int lane = t & 63;
    const int col  = lane & 15;
    const int quad = lane >> 4;

    bf16x8 Bg[3][4];
    bf16x8 Bh[3][2];
    float bgv[3], bhv[3];
    #pragma unroll
    for (int jt=0; jt<3; ++jt) {
        int J = jt*64 + 16*w + col;
        #pragma unroll
        for (int ks=0; ks<4; ++ks)
            Bg[jt][ks] = *(const bf16x8*)&Wg[J*128 + ks*32 + quad*8];
        #pragma unroll
        for (int ks=0; ks<2; ++ks)
            Bh[jt][ks] = *(const bf16x8*)&Wh[J*64 + ks*32 + quad*8];
        bgv[jt] = bg[J];
        bhv[jt] = bh[J];
    }

    __shared__ bf16 Alds[32][200];

    const int m_st = t >> 3;
    const int c_in = t & 7;

    for (int tb = blockIdx.x*32; tb < NN; tb += gridDim.x*32) {
        {
            long n = tb + m_st;
            // x1,x2: straight bf16x8 copies; h: fp32 -> bf16 convert
            *(bf16x8*)&Alds[m_st][c_in*8]      = *(const bf16x8*)&X1[n*HH + c_in*8];
            *(bf16x8*)&Alds[m_st][64 + c_in*8] = *(const bf16x8*)&X2[n*HH + c_in*8];
            const float4* rh = (const float4*)&H[n*HH];
            float4 a = rh[c_in*2], b4 = rh[c_in*2+1];
            bf16x8 hb = {(bf16)a.x,(bf16)a.y,(bf16)a.z,(bf16)a.w,
                         (bf16)b4.x,(bf16)b4.y,(bf16)b4.z,(bf16)b4.w};
            *(bf16x8*)&Alds[m_st][128 + c_in*8] = hb;
        }
        __syncthreads();

        f32x4 accg[2][3];
        f32x4 acch[2][3];
        #pragma unroll
        for (int mt=0; mt<2; ++mt)
            #pragma unroll
            for (int jt=0; jt<3; ++jt) {
                accg[mt][jt] = (f32x4){0.f,0.f,0.f,0.f};
                acch[mt][jt] = (f32x4){0.f,0.f,0.f,0.f};
            }

        #pragma unroll
        for (int ks=0; ks<4; ++ks) {
            #pragma unroll
            for (int mt=0; mt<2; ++mt) {
                bf16x8 a = *(const bf16x8*)&Alds[mt*16 + col][ks*32 + quad*8];
                #pragma unroll
                for (int jt=0; jt<3; ++jt)
                    accg[mt][jt] = __builtin_amdgcn_mfma_f32_16x16x32_bf16(
                        a, Bg[jt][ks], accg[mt][jt], 0, 0, 0);
            }
        }
        #pragma unroll
        for (int ks=0; ks<2; ++ks) {
            #pragma unroll
            for (int mt=0; mt<2; ++mt) {
                bf16x8 a = *(const bf16x8*)&Alds[mt*16 + col][128 + ks*32 + quad*8];
                #pragma unroll
                for (int jt=0; jt<3; ++jt)
                    acch[mt][jt] = __builtin_amdgcn_mfma_f32_16x16x32_bf16(
                        a, Bh[jt][ks], acch[mt][jt], 0, 0, 0);
            }
        }
        __syncthreads();

        const int c = 16*w + col;
        #pragma unroll
        for (int mt=0; mt<2; ++mt) {
            #pragma unroll
            for (int r=0; r<4; ++r) {
                long n = tb + mt*16 + quad*4 + r;
                float gr = accg[mt][0][r] + bgv[0];
                float gz = accg[mt][1][r] + bgv[1];
                float gn = accg[mt][2][r] + bgv[2];
                float hr = acch[mt][0][r] + bhv[0];
                float hz = acch[mt][1][r] + bhv[1];
                float hn = acch[mt][2][r] + bhv[2];
                float rr = fsig(gr + hr);
                float zz = fsig(gz + hz);
                float nv = ftanh(gn + rr*hn);
                float hv = H[n*HH + c];
                Hout[n*HH + c] = (1.0f - zz)*nv + zz*hv;
            }
        }
    }
}

extern "C" void kernel_launch(void* const* d_in, const int* in_sizes, int n_in,
                              void* d_out, int out_size, void* d_ws, size_t ws_size,
                              hipStream_t stream)
{
    const float* x       = (const float*)d_in[0];
    const int*   ei      = (const int*)  d_in[1];
    const float* ew      = (const float*)d_in[2];
    const int*   ei_re   = (const int*)  d_in[3];
    const float* ew_re   = (const float*)d_in[4];
    const float* W_first = (const float*)d_in[5];
    const float* b_first = (const float*)d_in[6];
    const float* W_con1  = (const float*)d_in[7];
    const float* b_con1  = (const float*)d_in[8];
    const float* W_con2  = (const float*)d_in[9];
    const float* b_con2  = (const float*)d_in[10];
    const float* W_lin1  = (const float*)d_in[11];
    const float* b_lin1  = (const float*)d_in[12];
    const float* W_out   = (const float*)d_in[13];
    const float* b_out   = (const float*)d_in[14];
    const float* W_ih    = (const float*)d_in[15];
    const float* W_hh    = (const float*)d_in[16];
    const float* b_ih    = (const float*)d_in[17];
    const float* b_hh    = (const float*)d_in[18];
    float* out = (float*)d_out;

    // ---- workspace layout
    float* h    = (float*)d_ws;            // [N*64] fp32 GRU state
    float* hA   = h  + (long)NN*HH;        // [N*64] fp32 (layer outputs / lin1 input)
    bf16*  x1b  = (bf16*)(hA + (long)NN*HH);   // [N*64]
    bf16*  x2b  = x1b + (long)NN*HH;           // [N*64]
    bf16*  hbf  = x2b + (long)NN*HH;           // [N*64]
    bf16*  hAbf = hbf + (long)NN*HH;           // [N*64]
    float* b1 = (float*)(hAbf + (long)NN*HH);  // [192]
    float* b2 = b1 + 192;                  // [192]
    bf16*  W1bf = (bf16*)(b2 + 192);       // [192*128]
    bf16*  W2bf = W1bf + 192*128;          // [192*128]
    bf16*  Whbf = W2bf + 192*128;          // [192*64]
    bf16*  Wfbf = Whbf + 192*64;           // [64*128]
    bf16*  Wlbf = Wfbf + 64*128;           // [64*64]
    bf16*  Wobf = Wlbf + 64*64;            // [16*64]
    int*   rp    = (int*)(Wobf + 16*64);   // [NSEG+1]
    int*   bkcur = rp + NSEG + 1;          // [NBUK]
    int*   tmp   = bkcur + NBUK;           // [NSEG]
    int*   bsum  = tmp + NSEG;             // [1024]
    int*   bscan = bsum + 1024;            // [1024]
    int2*  edata = (int2*)(bscan + 1024);  // [2E] final dst-sorted (src,w)
    // phase-A temporaries alias the bf16 node buffers (dead until after fillB)
    int*   tmp_d = (int*)x1b;              // [2E]  8 MB  (< 12.8 MB x1b)
    int2*  tmp_e = (int2*)x2b;             // [2E] 16 MB  (spans x2b+hbf = 25.6 MB)

    // 0) weights in bf16 (+ fp32 biases)
    precomp_kernel<<<(192*128 + 192 + 192*64 + 64*128 + 64*64 + 16*64 + 255)/256, 256, 0, stream>>>(
        W_ih, b_ih, W_con1, b_con1, W_con2, b_con2, W_hh, W_first, W_lin1, W_out,
        W1bf, b1, W2bf, b2, Whbf, Wfbf, Wlbf, Wobf);

    // 1) CSR build: count -> scan -> 2-phase bucket sort
    hipMemsetAsync(rp, 0, (size_t)(NSEG+1)*sizeof(int), stream);
    count_kernel<<<(2*EE + 255)/256, 256, 0, stream>>>(ei, ei_re, rp);
    scanA_kernel<<<NBLK, 256, 0, stream>>>(rp, tmp, bsum);
    scanB_kernel<<<1, 1024, 0, stream>>>(bsum, bscan);
    scanC_kernel<<<NBLK, 256, 0, stream>>>(tmp, bscan, rp, bkcur);
    fillA_kernel<<<P1BLK, 256, 0, stream>>>(ei, ew, ei_re, ew_re, bkcur, tmp_d, tmp_e);
    fillB_kernel<<<NBUK, 1024, 0, stream>>>(rp, tmp_d, tmp_e, edata);

    // 2) h = x @ W_first^T + b_first   (MFMA; fp32 + bf16 outputs)
    lin_first_mfma_kernel<<<1024, 256, 0, stream>>>(x, Wfbf, b_first, h, hbf);

    // 3) layer-1 propagation (bf16 gather)
    csr_prop_kernel<<<(NSEG + 3)/4, 256, 0, stream>>>(hbf, rp, edata, x1b, x2b);

    // 4) fused con1 + GRU -> hA   (MFMA)
    layer_mfma_kernel<<<1024, 256, 0, stream>>>(x1b, x2b, h, W1bf, b1, Whbf, b_hh, hA);

    // 5) lin1 -> hAbf (bf16, feeds prop only)
    lin64_mfma_kernel<<<1024, 256, 0, stream>>>(hA, Wlbf, b_lin1, hAbf);

    // 6) layer-2 propagation
    csr_prop_kernel<<<(NSEG + 3)/4, 256, 0, stream>>>(hAbf, rp, edata, x1b, x2b);

    // 7) fused con2 + GRU -> hA   (MFMA)
    layer_mfma_kernel<<<1024, 256, 0, stream>>>(x1b, x2b, h, W2bf, b2, Whbf, b_hh, hA);

    // 8) W_out + log_softmax   (MFMA)
    out_mfma_kernel<<<(NN + 127)/128, 256, 0, stream>>>(hA, Wobf, b_out, out);
}

// Round 8
// 440.170 us; speedup vs baseline: 6.6187x; 1.2800x over previous
//
#include <hip/hip_runtime.h>

#define NN 100000
#define FF 128
#define HH 64
#define CC 16
#define EE 1000000
#define NSEG (2*NN)                 // segments: [0,NN) = fwd, [NN,2NN) = rev
#define BSH 11                      // bucket = d >> 11 (2048 dsts/bucket)
#define BKD  (1 << BSH)
#define NBUK ((NSEG + BKD - 1) / BKD)   // 98
#define EPB 4096                    // edges per fillA/bucket_count block
#define P1BLK ((2*EE + EPB - 1) / EPB)

typedef __bf16 bf16;
typedef __attribute__((ext_vector_type(8))) __bf16 bf16x8;
typedef __attribute__((ext_vector_type(4))) __bf16 bf16x4;
typedef __attribute__((ext_vector_type(4))) float f32x4;

__device__ __forceinline__ float fsig(float t)  { return 1.0f/(1.0f+__expf(-t)); }
__device__ __forceinline__ float ftanh(float t) { return 1.0f - 2.0f/(__expf(2.0f*t)+1.0f); }

// pack (src, w>=0) into 4 B: src(17 bits) << 15 | bf16(w) sans sign (15 bits)
__device__ __forceinline__ unsigned pack_sw(int s, float w) {
    unsigned short u = __builtin_bit_cast(unsigned short, (bf16)w);
    return ((unsigned)s << 15) | (u & 0x7FFFu);
}

// ---- Combined weights in bf16 + bf16 copies of W_first / W_lin1 / W_out
__global__ void precomp_kernel(const float* __restrict__ W_ih, const float* __restrict__ b_ih,
                               const float* __restrict__ Wc1,  const float* __restrict__ bc1,
                               const float* __restrict__ Wc2,  const float* __restrict__ bc2,
                               const float* __restrict__ W_hh, const float* __restrict__ W_first,
                               const float* __restrict__ W_lin1, const float* __restrict__ W_out,
                               bf16* __restrict__ W1bf, float* __restrict__ b1,
                               bf16* __restrict__ W2bf, float* __restrict__ b2,
                               bf16* __restrict__ Whbf, bf16* __restrict__ Wfbf,
                               bf16* __restrict__ Wlbf, bf16* __restrict__ Wobf)
{
    int idx = blockIdx.x*blockDim.x + threadIdx.x;
    const int t0 = 192*128;          // W1/W2
    const int t1 = t0 + 192;         // b1/b2
    const int t2 = t1 + 192*64;      // Whbf
    const int t3 = t2 + 64*128;      // Wfbf
    const int t4 = t3 + 64*64;       // Wlbf
    const int t5 = t4 + 16*64;       // Wobf
    if (idx < t0) {
        int j = idx >> 7, k = idx & 127;
        float s1 = 0.f, s2 = 0.f;
        for (int m=0; m<64; ++m) {
            float wih = W_ih[j*64+m];
            s1 += wih * Wc1[m*128+k];
            s2 += wih * Wc2[m*128+k];
        }
        W1bf[idx] = (bf16)s1; W2bf[idx] = (bf16)s2;
    } else if (idx < t1) {
        int j = idx - t0;
        float s1 = b_ih[j], s2 = b_ih[j];
        for (int m=0; m<64; ++m) {
            float wih = W_ih[j*64+m];
            s1 += wih * bc1[m];
            s2 += wih * bc2[m];
        }
        b1[j] = s1; b2[j] = s2;
    } else if (idx < t2) {
        int i = idx - t1;  Whbf[i] = (bf16)W_hh[i];
    } else if (idx < t3) {
        int i = idx - t2;  Wfbf[i] = (bf16)W_first[i];
    } else if (idx < t4) {
        int i = idx - t3;  Wlbf[i] = (bf16)W_lin1[i];
    } else if (idx < t5) {
        int i = idx - t4;  Wobf[i] = (bf16)W_out[i];
    }
}

// ================= CSR build: bucketed 2-phase sort, no global count/scan =================

// coarse bucket histogram (98 buckets) via LDS
__global__ __launch_bounds__(256) void bucket_count_kernel(const int* __restrict__ ei,
                                                           const int* __restrict__ ei_re,
                                                           int* __restrict__ bkcnt)
{
    __shared__ int hist[NBUK];
    const int t = threadIdx.x;
    for (int i=t; i<NBUK; i+=256) hist[i] = 0;
    __syncthreads();
    const long e0 = (long)blockIdx.x * EPB;
    #pragma unroll
    for (int it=0; it<16; ++it) {
        long e = e0 + it*256 + t;
        int d = -1;
        if (e < EE)        d = ei[EE + e];
        else if (e < 2*EE) d = NN + ei_re[EE + (e - EE)];
        if (d >= 0) atomicAdd(&hist[d >> BSH], 1);
    }
    __syncthreads();
    for (int i=t; i<NBUK; i+=256) if (hist[i]) atomicAdd(&bkcnt[i], hist[i]);
}

// scan 98 bucket counts (1 block); also rp[NSEG] terminator
__global__ void bucket_scan_kernel(const int* __restrict__ bkcnt,
                                   int* __restrict__ bkbase, int* __restrict__ bkcur,
                                   int* __restrict__ rp)
{
    if (threadIdx.x == 0) {
        int acc = 0;
        for (int i=0; i<NBUK; ++i) { bkbase[i] = acc; bkcur[i] = acc; acc += bkcnt[i]; }
        bkbase[NBUK] = acc;          // = 2E
        rp[NSEG] = 2*EE;
    }
}

// Phase A: bucket edges into contiguous per-block runs (each output line
// written by ONE block -> no cross-XCD partial-line writebacks).
__global__ __launch_bounds__(256) void fillA_kernel(const int* __restrict__ ei,
                                                    const float* __restrict__ ew,
                                                    const int* __restrict__ ei_re,
                                                    const float* __restrict__ ew_re,
                                                    int* __restrict__ bkcur,
                                                    int* __restrict__ tmp_d,
                                                    unsigned* __restrict__ tmp_p)
{
    __shared__ int hist[NBUK];
    __shared__ int base[NBUK];
    const int t = threadIdx.x;
    for (int i=t; i<NBUK; i+=256) hist[i] = 0;
    __syncthreads();
    const long e0 = (long)blockIdx.x * EPB;
    int pr[16];
    #pragma unroll
    for (int it=0; it<16; ++it) {
        long e = e0 + it*256 + t;
        int d = -1;
        if (e < EE)        d = ei[EE + e];
        else if (e < 2*EE) d = NN + ei_re[EE + (e - EE)];
        if (d >= 0) {
            int b = d >> BSH;
            int r = atomicAdd(&hist[b], 1);
            pr[it] = (b << 16) | r;
        } else pr[it] = -1;
    }
    __syncthreads();
    for (int i=t; i<NBUK; i+=256) base[i] = atomicAdd(&bkcur[i], hist[i]);
    __syncthreads();
    #pragma unroll
    for (int it=0; it<16; ++it) {
        if (pr[it] < 0) continue;
        long e = e0 + it*256 + t;
        int d, s; float w;
        if (e < EE) { d = ei[EE+e]; s = ei[e]; w = ew[e]; }
        else { long j = e - EE; d = NN + ei_re[EE+j]; s = ei_re[j]; w = ew_re[j]; }
        int pos = base[pr[it] >> 16] + (pr[it] & 0xFFFF);
        tmp_d[pos] = d;
        tmp_p[pos] = pack_sw(s, w);
    }
}

// Phase B: one block per bucket. LDS per-dst count -> LDS scan -> write rp,
// then place edges (scattered writes confined to this bucket's window).
__global__ __launch_bounds__(1024) void fillB_kernel(const int* __restrict__ bkbase,
                                                     const int* __restrict__ tmp_d,
                                                     const unsigned* __restrict__ tmp_p,
                                                     unsigned* __restrict__ edata,
                                                     int* __restrict__ rp)
{
    __shared__ int cntL[BKD];      // counts -> later global cursors
    __shared__ int scanL[1024];    // pair-sum scan workspace
    const int t  = threadIdx.x;
    const int b  = blockIdx.x;
    const int d0 = b << BSH;
    const int dn = min(BKD, NSEG - d0);
    const int p0 = bkbase[b];
    const int p1 = bkbase[b+1];
    for (int i=t; i<BKD; i+=1024) cntL[i] = 0;
    __syncthreads();
    for (int pos = p0 + t; pos < p1; pos += 1024)
        atomicAdd(&cntL[tmp_d[pos] - d0], 1);
    __syncthreads();
    // exclusive scan over 2048 via pair-sums (each thread owns 2 elements)
    int a0 = cntL[2*t], a1 = cntL[2*t+1];
    int ps = a0 + a1;
    scanL[t] = ps;
    __syncthreads();
    #pragma unroll
    for (int off=1; off<1024; off<<=1) {
        int x = (t>=off) ? scanL[t-off] : 0;
        __syncthreads();
        scanL[t] += x;
        __syncthreads();
    }
    int g0 = p0 + scanL[t] - ps;   // exclusive base of element 2t
    int g1 = g0 + a0;
    if (2*t   < dn) rp[d0 + 2*t]   = g0;
    if (2*t+1 < dn) rp[d0 + 2*t+1] = g1;
    cntL[2*t]   = g0;              // reuse as global cursors
    cntL[2*t+1] = g1;
    __syncthreads();
    for (int pos = p0 + t; pos < p1; pos += 1024) {
        int d = tmp_d[pos];
        int p = atomicAdd(&cntL[d - d0], 1);
        edata[p] = tmp_p[pos];
    }
}

// gather segment-sum: masked 8-deep unroll keeps 8 gathers in flight
__global__ __launch_bounds__(256) void csr_prop_kernel(const bf16* __restrict__ X,
    const int* __restrict__ rp, const unsigned* __restrict__ edata,
    bf16* __restrict__ x1, bf16* __restrict__ x2)
{
    int s = blockIdx.x*4 + (threadIdx.x>>6);
    if (s >= NSEG) return;
    int lane = threadIdx.x & 63;
    int e0 = rp[s], e1 = rp[s+1];
    float acc = 0.f;
    for (int e = e0; e < e1; e += 8) {
        unsigned pk[8]; float vw[8];
        #pragma unroll
        for (int j=0;j<8;++j) {
            int idx = e + j;
            unsigned p = edata[idx < e1 ? idx : e0];
            pk[j] = p;
            vw[j] = (idx < e1) ? __uint_as_float((p & 0x7FFFu) << 16) : 0.f;
        }
        float xv[8];
        #pragma unroll
        for (int j=0;j<8;++j) xv[j] = (float)X[(long)(pk[j] >> 15)*HH + lane];
        #pragma unroll
        for (int j=0;j<8;++j) acc += vw[j]*xv[j];
    }
    bf16* o = (s < NN) ? &x1[(long)s*HH] : &x2[(long)(s-NN)*HH];
    o[lane] = (bf16)acc;
}

// ================= dense kernels: all MFMA (unchanged from R7) =================

__global__ __launch_bounds__(256, 2) void lin_first_mfma_kernel(
    const float* __restrict__ X, const bf16* __restrict__ Wf,
    const float* __restrict__ b, float* __restrict__ Y, bf16* __restrict__ Ybf)
{
    const int t = threadIdx.x;
    const int w = t >> 6, lane = t & 63, col = lane & 15, quad = lane >> 4;
    bf16x8 B[4];
    #pragma unroll
    for (int ks=0; ks<4; ++ks)
        B[ks] = *(const bf16x8*)&Wf[(16*w+col)*128 + ks*32 + quad*8];
    const float bv = b[16*w + col];
    __shared__ bf16 Alds[32][136];
    const int m_st = t >> 3, c_in = t & 7;
    for (int tb = blockIdx.x*32; tb < NN; tb += gridDim.x*32) {
        const float4* rx = (const float4*)&X[(long)(tb+m_st)*FF];
        #pragma unroll
        for (int it=0; it<4; ++it) {
            int cc = c_in + it*8;
            float4 v = rx[cc];
            bf16x4 bvv = {(bf16)v.x,(bf16)v.y,(bf16)v.z,(bf16)v.w};
            *(bf16x4*)&Alds[m_st][cc*4] = bvv;
        }
        __syncthreads();
        f32x4 acc[2] = {{0.f,0.f,0.f,0.f},{0.f,0.f,0.f,0.f}};
        #pragma unroll
        for (int ks=0; ks<4; ++ks)
            #pragma unroll
            for (int mt=0; mt<2; ++mt) {
                bf16x8 a = *(const bf16x8*)&Alds[mt*16+col][ks*32+quad*8];
                acc[mt] = __builtin_amdgcn_mfma_f32_16x16x32_bf16(a, B[ks], acc[mt], 0,0,0);
            }
        __syncthreads();
        #pragma unroll
        for (int mt=0; mt<2; ++mt)
            #pragma unroll
            for (int r=0; r<4; ++r) {
                long n = tb + mt*16 + quad*4 + r;
                float val = acc[mt][r] + bv;
                Y  [n*HH + 16*w+col] = val;
                Ybf[n*HH + 16*w+col] = (bf16)val;
            }
    }
}

__global__ __launch_bounds__(256, 2) void lin64_mfma_kernel(
    const float* __restrict__ X, const bf16* __restrict__ Wl,
    const float* __restrict__ b, bf16* __restrict__ Ybf)
{
    const int t = threadIdx.x;
    const int w = t >> 6, lane = t & 63, col = lane & 15, quad = lane >> 4;
    bf16x8 B[2];
    #pragma unroll
    for (int ks=0; ks<2; ++ks)
        B[ks] = *(const bf16x8*)&Wl[(16*w+col)*64 + ks*32 + quad*8];
    const float bv = b[16*w + col];
    __shared__ bf16 Alds[32][72];
    const int m_st = t >> 3, c_in = t & 7;
    for (int tb = blockIdx.x*32; tb < NN; tb += gridDim.x*32) {
        const float4* rx = (const float4*)&X[(long)(tb+m_st)*HH];
        #pragma unroll
        for (int it=0; it<2; ++it) {
            int cc = c_in + it*8;
            float4 v = rx[cc];
            bf16x4 bvv = {(bf16)v.x,(bf16)v.y,(bf16)v.z,(bf16)v.w};
            *(bf16x4*)&Alds[m_st][cc*4] = bvv;
        }
        __syncthreads();
        f32x4 acc[2] = {{0.f,0.f,0.f,0.f},{0.f,0.f,0.f,0.f}};
        #pragma unroll
        for (int ks=0; ks<2; ++ks)
            #pragma unroll
            for (int mt=0; mt<2; ++mt) {
                bf16x8 a = *(const bf16x8*)&Alds[mt*16+col][ks*32+quad*8];
                acc[mt] = __builtin_amdgcn_mfma_f32_16x16x32_bf16(a, B[ks], acc[mt], 0,0,0);
            }
        __syncthreads();
        #pragma unroll
        for (int mt=0; mt<2; ++mt)
            #pragma unroll
            for (int r=0; r<4; ++r)
                Ybf[(long)(tb+mt*16+quad*4+r)*HH + 16*w+col] = (bf16)(acc[mt][r] + bv);
    }
}

__global__ __launch_bounds__(256) void out_mfma_kernel(
    const float* __restrict__ X, const bf16* __restrict__ Wo,
    const float* __restrict__ b, float* __restrict__ Y)
{
    const int t = threadIdx.x;
    const int w = t >> 6, lane = t & 63, col = lane & 15, quad = lane >> 4;
    bf16x8 B[2];
    #pragma unroll
    for (int ks=0; ks<2; ++ks)
        B[ks] = *(const bf16x8*)&Wo[col*64 + ks*32 + quad*8];
    const float bv = b[col];
    __shared__ bf16 Alds[128][72];
    const int r_st = t >> 1, sub = t & 1;
    const int tb = blockIdx.x*128;
    {
        const float4* rx = (const float4*)&X[(long)(tb+r_st)*HH];
        #pragma unroll
        for (int it=0; it<8; ++it) {
            int cc = sub*8 + it;
            float4 v = rx[cc];
            bf16x4 bvv = {(bf16)v.x,(bf16)v.y,(bf16)v.z,(bf16)v.w};
            *(bf16x4*)&Alds[r_st][cc*4] = bvv;
        }
    }
    __syncthreads();
    f32x4 acc[2] = {{0.f,0.f,0.f,0.f},{0.f,0.f,0.f,0.f}};
    #pragma unroll
    for (int ks=0; ks<2; ++ks)
        #pragma unroll
        for (int mt=0; mt<2; ++mt) {
            bf16x8 a = *(const bf16x8*)&Alds[w*32 + mt*16 + col][ks*32+quad*8];
            acc[mt] = __builtin_amdgcn_mfma_f32_16x16x32_bf16(a, B[ks], acc[mt], 0,0,0);
        }
    #pragma unroll
    for (int mt=0; mt<2; ++mt) {
        #pragma unroll
        for (int r=0; r<4; ++r) {
            int n = tb + w*32 + mt*16 + quad*4 + r;
            float val = acc[mt][r] + bv;
            float m = val;
            #pragma unroll
            for (int off=8; off>0; off>>=1) m = fmaxf(m, __shfl_xor(m, off, 16));
            float ex = __expf(val - m);
            float s = ex;
            #pragma unroll
            for (int off=8; off>0; off>>=1) s += __shfl_xor(s, off, 16);
            if (n < NN) Y[(long)n*CC + col] = val - m - __logf(s);
        }
    }
}

__global__ __launch_bounds__(256, 2) void layer_mfma_kernel(
    const bf16* __restrict__ X1, const bf16* __restrict__ X2,
    const float* __restrict__ H,
    const bf16* __restrict__ Wg, const float* __restrict__ bg,
    const bf16* __restrict__ Wh, const float* __restrict__ bh,
    float* __restrict__ Hout)
{
    const int t    = threadIdx.x;
    const int w    = t >> 6;
    const int lane = t & 63;
    const int col  = lane & 15;
    const int quad = lane >> 4;

    bf16x8 Bg[3][4];
    bf16x8 Bh[3][2];
    float bgv[3], bhv[3];
    #pragma unroll
    for (int jt=0; jt<3; ++jt) {
        int J = jt*64 + 16*w + col;
        #pragma unroll
        for (int ks=0; ks<4; ++ks)
            Bg[jt][ks] = *(const bf16x8*)&Wg[J*128 + ks*32 + quad*8];
        #pragma unroll
        for (int ks=0; ks<2; ++ks)
            Bh[jt][ks] = *(const bf16x8*)&Wh[J*64 + ks*32 + quad*8];
        bgv[jt] = bg[J];
        bhv[jt] = bh[J];
    }

    __shared__ bf16 Alds[32][200];

    const int m_st = t >> 3;
    const int c_in = t & 7;

    for (int tb = blockIdx.x*32; tb < NN; tb += gridDim.x*32) {
        {
            long n = tb + m_st;
            *(bf16x8*)&Alds[m_st][c_in*8]      = *(const bf16x8*)&X1[n*HH + c_in*8];
            *(bf16x8*)&Alds[m_st][64 + c_in*8] = *(const bf16x8*)&X2[n*HH + c_in*8];
            const float4* rh = (const float4*)&H[n*HH];
            float4 a = rh[c_in*2], b4 = rh[c_in*2+1];
            bf16x8 hb = {(bf16)a.x,(bf16)a.y,(bf16)a.z,(bf16)a.w,
                         (bf16)b4.x,(bf16)b4.y,(bf16)b4.z,(bf16)b4.w};
            *(bf16x8*)&Alds[m_st][128 + c_in*8] = hb;
        }
        __syncthreads();

        f32x4 accg[2][3];
        f32x4 acch[2][3];
        #pragma unroll
        for (int mt=0; mt<2; ++mt)
            #pragma unroll
            for (int jt=0; jt<3; ++jt) {
                accg[mt][jt] = (f32x4){0.f,0.f,0.f,0.f};
                acch[mt][jt] = (f32x4){0.f,0.f,0.f,0.f};
            }

        #pragma unroll
        for (int ks=0; ks<4; ++ks) {
            #pragma unroll
            for (int mt=0; mt<2; ++mt) {
                bf16x8 a = *(const bf16x8*)&Alds[mt*16 + col][ks*32 + quad*8];
                #pragma unroll
                for (int jt=0; jt<3; ++jt)
                    accg[mt][jt] = __builtin_amdgcn_mfma_f32_16x16x32_bf16(
                        a, Bg[jt][ks], accg[mt][jt], 0, 0, 0);
            }
        }
        #pragma unroll
        for (int ks=0; ks<2; ++ks) {
            #pragma unroll
            for (int mt=0; mt<2; ++mt) {
                bf16x8 a = *(const bf16x8*)&Alds[mt*16 + col][128 + ks*32 + quad*8];
                #pragma unroll
                for (int jt=0; jt<3; ++jt)
                    acch[mt][jt] = __builtin_amdgcn_mfma_f32_16x16x32_bf16(
                        a, Bh[jt][ks], acch[mt][jt], 0, 0, 0);
            }
        }
        __syncthreads();

        const int c = 16*w + col;
        #pragma unroll
        for (int mt=0; mt<2; ++mt) {
            #pragma unroll
            for (int r=0; r<4; ++r) {
                long n = tb + mt*16 + quad*4 + r;
                float gr = accg[mt][0][r] + bgv[0];
                float gz = accg[mt][1][r] + bgv[1];
                float gn = accg[mt][2][r] + bgv[2];
                float hr = acch[mt][0][r] + bhv[0];
                float hz = acch[mt][1][r] + bhv[1];
                float hn = acch[mt][2][r] + bhv[2];
                float rr = fsig(gr + hr);
                float zz = fsig(gz + hz);
                float nv = ftanh(gn + rr*hn);
                float hv = H[n*HH + c];
                Hout[n*HH + c] = (1.0f - zz)*nv + zz*hv;
            }
        }
    }
}

extern "C" void kernel_launch(void* const* d_in, const int* in_sizes, int n_in,
                              void* d_out, int out_size, void* d_ws, size_t ws_size,
                              hipStream_t stream)
{
    const float* x       = (const float*)d_in[0];
    const int*   ei      = (const int*)  d_in[1];
    const float* ew      = (const float*)d_in[2];
    const int*   ei_re   = (const int*)  d_in[3];
    const float* ew_re   = (const float*)d_in[4];
    const float* W_first = (const float*)d_in[5];
    const float* b_first = (const float*)d_in[6];
    const float* W_con1  = (const float*)d_in[7];
    const float* b_con1  = (const float*)d_in[8];
    const float* W_con2  = (const float*)d_in[9];
    const float* b_con2  = (const float*)d_in[10];
    const float* W_lin1  = (const float*)d_in[11];
    const float* b_lin1  = (const float*)d_in[12];
    const float* W_out   = (const float*)d_in[13];
    const float* b_out   = (const float*)d_in[14];
    const float* W_ih    = (const float*)d_in[15];
    const float* W_hh    = (const float*)d_in[16];
    const float* b_ih    = (const float*)d_in[17];
    const float* b_hh    = (const float*)d_in[18];
    float* out = (float*)d_out;

    // ---- workspace layout
    float* h    = (float*)d_ws;                // [N*64] fp32 GRU state
    float* hA   = h  + (long)NN*HH;            // [N*64] fp32 layer output
    bf16*  x1b  = (bf16*)(hA + (long)NN*HH);   // [N*64]
    bf16*  x2b  = x1b + (long)NN*HH;           // [N*64]
    bf16*  hbf  = x2b + (long)NN*HH;           // [N*64]
    bf16*  hAbf = hbf + (long)NN*HH;           // [N*64]
    float* b1 = (float*)(hAbf + (long)NN*HH);  // [192]
    float* b2 = b1 + 192;                      // [192]
    bf16*  W1bf = (bf16*)(b2 + 192);           // [192*128]
    bf16*  W2bf = W1bf + 192*128;
    bf16*  Whbf = W2bf + 192*128;
    bf16*  Wfbf = Whbf + 192*64;
    bf16*  Wlbf = Wfbf + 64*128;
    bf16*  Wobf = Wlbf + 64*64;
    int*   rp     = (int*)(Wobf + 16*64);      // [NSEG+1]
    int*   bkcnt  = rp + NSEG + 1;             // [NBUK]
    int*   bkbase = bkcnt + NBUK;              // [NBUK+1]
    int*   bkcur  = bkbase + NBUK + 1;         // [NBUK]
    unsigned* edata = (unsigned*)(bkcur + NBUK); // [2E] packed (src,w), dst-sorted
    // phase-A temporaries alias the bf16 node buffers (dead until after fillB)
    int*      tmp_d = (int*)x1b;               // [2E] 8 MB
    unsigned* tmp_p = (unsigned*)x2b;          // [2E] 8 MB

    // 0) weights in bf16 (+ fp32 biases)
    precomp_kernel<<<(192*128 + 192 + 192*64 + 64*128 + 64*64 + 16*64 + 255)/256, 256, 0, stream>>>(
        W_ih, b_ih, W_con1, b_con1, W_con2, b_con2, W_hh, W_first, W_lin1, W_out,
        W1bf, b1, W2bf, b2, Whbf, Wfbf, Wlbf, Wobf);

    // 1) CSR build: bucket-count -> 98-scan -> 2-phase sort (fillB also emits rp)
    hipMemsetAsync(bkcnt, 0, (size_t)NBUK*sizeof(int), stream);
    bucket_count_kernel<<<P1BLK, 256, 0, stream>>>(ei, ei_re, bkcnt);
    bucket_scan_kernel<<<1, 64, 0, stream>>>(bkcnt, bkbase, bkcur, rp);
    fillA_kernel<<<P1BLK, 256, 0, stream>>>(ei, ew, ei_re, ew_re, bkcur, tmp_d, tmp_p);
    fillB_kernel<<<NBUK, 1024, 0, stream>>>(bkbase, tmp_d, tmp_p, edata, rp);

    // 2) h = x @ W_first^T + b_first   (MFMA; fp32 + bf16 outputs)
    lin_first_mfma_kernel<<<1024, 256, 0, stream>>>(x, Wfbf, b_first, h, hbf);

    // 3) layer-1 propagation (bf16 gather, packed edges)
    csr_prop_kernel<<<(NSEG + 3)/4, 256, 0, stream>>>(hbf, rp, edata, x1b, x2b);

    // 4) fused con1 + GRU -> hA   (MFMA)
    layer_mfma_kernel<<<1024, 256, 0, stream>>>(x1b, x2b, h, W1bf, b1, Whbf, b_hh, hA);

    // 5) lin1 -> hAbf (bf16, feeds prop only)
    lin64_mfma_kernel<<<1024, 256, 0, stream>>>(hA, Wlbf, b_lin1, hAbf);

    // 6) layer-2 propagation
    csr_prop_kernel<<<(NSEG + 3)/4, 256, 0, stream>>>(hAbf, rp, edata, x1b, x2b);

    // 7) fused con2 + GRU -> hA   (MFMA)
    layer_mfma_kernel<<<1024, 256, 0, stream>>>(x1b, x2b, h, W2bf, b2, Whbf, b_hh, hA);

    // 8) W_out + log_softmax   (MFMA)
    out_mfma_kernel<<<(NN + 127)/128, 256, 0, stream>>>(hA, Wobf, b_out, out);
}